// Round 10
// baseline (1038.829 us; speedup 1.0000x reference)
//
#include <hip/hip_runtime.h>
#include <hip/hip_bf16.h>

#define D_IN 128
#define D_EMB 64

typedef float f32x2 __attribute__((ext_vector_type(2)));
typedef float f32x4v __attribute__((ext_vector_type(4)));
typedef short bf16x8 __attribute__((ext_vector_type(8)));   // 8 bf16 = 4 VGPRs (guide §3)

static __device__ __forceinline__ unsigned short f2bf(float f) {
  __hip_bfloat16 h = __float2bfloat16(f);
  return *(unsigned short*)&h;
}

// ---- MFMA weight prep: W[64][K] fp32 -> packed bf16 B-fragments.
// frag index tid=(s*4+ct)*64+lane holds W[ct*16+(lane&15)][s*32+(lane>>4)*8 + j], j=0..7
__global__ __launch_bounds__(256) void wprep_mfma_k(const float* __restrict__ W,
                                                    unsigned short* __restrict__ out,
                                                    int K) {
  int tid = blockIdx.x * 256 + threadIdx.x;
  int total = (K / 32) * 4 * 64;
  if (tid >= total) return;
  int lane = tid & 63;
  int ct = (tid >> 6) & 3;
  int s = tid >> 8;
  int row = ct * 16 + (lane & 15);
  int kk = s * 32 + (lane >> 4) * 8;
  unsigned short tmp[8];
#pragma unroll
  for (int j = 0; j < 8; j++) tmp[j] = f2bf(W[row * K + kk + j]);
  *(uint4*)&out[(size_t)tid * 8] = *(uint4*)tmp;
}

// ==== CSR build (round-17 design, proven): src-sort pass 0 + dst-sub sort ====

// Per-chunk 256-bin histogram of key>>9, written TRANSPOSED h[bin*1024+chunk].
__global__ __launch_bounds__(256) void bhist1_k(const int* __restrict__ key,
                                                int* __restrict__ bh, int E) {
  __shared__ int h[256];
  const int t = threadIdx.x;
  h[t] = 0;
  __syncthreads();
  const int base = blockIdx.x * 2048;
#pragma unroll
  for (int j = 0; j < 8; j++) {
    int e = base + j * 256 + t;
    if (e < E) atomicAdd(&h[key[e] >> 9], 1);
  }
  __syncthreads();
  bh[t * 1024 + blockIdx.x] = h[t];
}

// Per-bin exclusive scan over the 1024 chunks (one block per bin), in place.
__global__ __launch_bounds__(256) void scanA_k(int* __restrict__ bh,
                                               int* __restrict__ bintot) {
  __shared__ int sa[256], sb[256];
  const int t = threadIdx.x;
  int* row = bh + (size_t)blockIdx.x * 1024;
  int v0 = row[t * 4], v1 = row[t * 4 + 1], v2 = row[t * 4 + 2], v3 = row[t * 4 + 3];
  int sum = v0 + v1 + v2 + v3;
  sa[t] = sum;
  __syncthreads();
  int* in = sa;
  int* out = sb;
  for (int st = 1; st < 256; st <<= 1) {
    out[t] = in[t] + (t >= st ? in[t - st] : 0);
    __syncthreads();
    int* tmp = in; in = out; out = tmp;
  }
  int excl = in[t] - sum;
  row[t * 4] = excl;
  row[t * 4 + 1] = excl + v0;
  row[t * 4 + 2] = excl + v0 + v1;
  row[t * 4 + 3] = excl + v0 + v1 + v2;
  if (t == 255) bintot[blockIdx.x] = in[255];
}

// Exclusive scan of the 256 bin totals -> base[256] bucket starts, base[256]=E.
__global__ __launch_bounds__(256) void scanB_k(const int* __restrict__ bintot,
                                               int* __restrict__ base) {
  __shared__ int sa[256], sb[256];
  const int t = threadIdx.x;
  int v = bintot[t];
  sa[t] = v;
  __syncthreads();
  int* in = sa;
  int* out = sb;
  for (int st = 1; st < 256; st <<= 1) {
    out[t] = in[t] + (t >= st ? in[t - st] : 0);
    __syncthreads();
    int* tmp = in; in = out; out = tmp;
  }
  base[t] = in[t] - v;
  if (t == 255) base[256] = in[255];
}

// Pass-0 fill: LDS chunk counting-sort by src>>9, emits parallel (srcS, dstS).
__global__ __launch_bounds__(256) void sfill_k(const int* __restrict__ src,
                                               const int* __restrict__ dst,
                                               const int* __restrict__ sh,
                                               const int* __restrict__ ssub,
                                               int* __restrict__ srcS,
                                               int* __restrict__ dstS, int E) {
  __shared__ int hA[256], hB[256], runCur[256], gb[256];
  __shared__ int scache[2048];
  __shared__ int dcache[2048];
  __shared__ int sortS[2048];
  __shared__ int sortD[2048];
  __shared__ unsigned short subb[2048];
  const int t = threadIdx.x;
  const int base = blockIdx.x * 2048;
  const int n = min(2048, E - base);
  hA[t] = 0;
  __syncthreads();
#pragma unroll
  for (int j = 0; j < 8; j++) {
    int idx = j * 256 + t;
    int e = base + idx;
    if (idx < n) {
      int s = src[e];
      scache[idx] = s;
      dcache[idx] = dst[e];
      atomicAdd(&hA[s >> 9], 1);
    }
  }
  __syncthreads();
  int cnt = hA[t];
  int* in = hA;
  int* out = hB;
  for (int st = 1; st < 256; st <<= 1) {
    out[t] = in[t] + (t >= st ? in[t - st] : 0);
    __syncthreads();
    int* tmp = in; in = out; out = tmp;
  }
  int rs = in[t] - cnt;
  __syncthreads();
  hB[t] = rs;
  runCur[t] = rs;
  gb[t] = ssub[t] + sh[t * 1024 + blockIdx.x];
  __syncthreads();
#pragma unroll
  for (int j = 0; j < 8; j++) {
    int idx = j * 256 + t;
    if (idx < n) {
      int s = scache[idx];
      int b = s >> 9;
      int lpos = atomicAdd(&runCur[b], 1);
      sortS[lpos] = s;
      sortD[lpos] = dcache[idx];
      subb[lpos] = (unsigned short)b;
    }
  }
  __syncthreads();
  for (int idx = t; idx < n; idx += 256) {
    int b = subb[idx];
    int g = gb[b] + idx - hB[b];
    srcS[g] = sortS[idx];
    dstS[g] = sortD[idx];
  }
}

// Pass-1 fill: LDS chunk counting-sort by dst>>9 reading the src-sorted
// arrays (stable at chunk level -> dst-sub entries stay src-ordered).
// Packed word: (dst&511)<<17 | src  (9b node-in-sub + 17b src, N=2^17).
__global__ __launch_bounds__(256) void bfill1_k(const int* __restrict__ src,
                                                const int* __restrict__ dst,
                                                const int* __restrict__ bh,
                                                const int* __restrict__ sbase,
                                                unsigned int* __restrict__ bkt,
                                                int E) {
  __shared__ int hA[256], hB[256], runCur[256], gb[256];
  __shared__ int dcache[2048];
  __shared__ unsigned int sorted[2048];
  __shared__ unsigned short subb[2048];
  const int t = threadIdx.x;
  const int base = blockIdx.x * 2048;
  const int n = min(2048, E - base);
  hA[t] = 0;
  __syncthreads();
#pragma unroll
  for (int j = 0; j < 8; j++) {
    int idx = j * 256 + t;
    int e = base + idx;
    if (idx < n) {
      int d = dst[e];
      dcache[idx] = d;
      atomicAdd(&hA[d >> 9], 1);
    }
  }
  __syncthreads();
  int cnt = hA[t];
  int* in = hA;
  int* out = hB;
  for (int st = 1; st < 256; st <<= 1) {
    out[t] = in[t] + (t >= st ? in[t - st] : 0);
    __syncthreads();
    int* tmp = in; in = out; out = tmp;
  }
  int rs = in[t] - cnt;
  __syncthreads();
  hB[t] = rs;
  runCur[t] = rs;
  gb[t] = sbase[t] + bh[t * 1024 + blockIdx.x];
  __syncthreads();
#pragma unroll
  for (int j = 0; j < 8; j++) {
    int idx = j * 256 + t;
    int e = base + idx;
    if (idx < n) {
      int d = dcache[idx];
      int b = d >> 9;
      int lpos = atomicAdd(&runCur[b], 1);
      sorted[lpos] = ((unsigned)(d & 511) << 17) | (unsigned)src[e];
      subb[lpos] = (unsigned short)b;
    }
  }
  __syncthreads();
  for (int idx = t; idx < n; idx += 256) {
    int b = subb[idx];
    bkt[gb[b] + idx - hB[b]] = sorted[idx];
  }
}

// Per-sub degree count (own contiguous sub-bucket, 32 iters, atomic-free write).
__global__ __launch_bounds__(256) void deg4_k(const unsigned int* __restrict__ bkt,
                                              const int* __restrict__ sbase,
                                              int* __restrict__ deg) {
  __shared__ int h[512];
  const int t = threadIdx.x;
  h[t] = 0;
  h[t + 256] = 0;
  __syncthreads();
  const int i = blockIdx.x;
  const int lo = sbase[i], hi = sbase[i + 1];
  for (int e = lo + t; e < hi; e += 256) atomicAdd(&h[bkt[e] >> 17], 1);
  __syncthreads();
  deg[i * 512 + t] = h[t];
  deg[i * 512 + t + 256] = h[t + 256];
}

__global__ __launch_bounds__(256) void blocksum_k(const int* __restrict__ deg,
                                                  int* __restrict__ bsum) {
  __shared__ int sm[256];
  int t = threadIdx.x;
  sm[t] = deg[blockIdx.x * 256 + t];
  __syncthreads();
  for (int s = 128; s > 0; s >>= 1) {
    if (t < s) sm[t] += sm[t + s];
    __syncthreads();
  }
  if (t == 0) bsum[blockIdx.x] = sm[0];
}

// single block: exclusive scan of 512 block sums (in place)
__global__ __launch_bounds__(256) void scanbsum_k(int* __restrict__ bsum) {
  __shared__ int a[512], b[512];
  int t = threadIdx.x;
  a[t] = bsum[t];
  a[t + 256] = bsum[t + 256];
  __syncthreads();
  int* in = a;
  int* out = b;
  for (int st = 1; st < 512; st <<= 1) {
    for (int i = t; i < 512; i += 256) out[i] = in[i] + (i >= st ? in[i - st] : 0);
    __syncthreads();
    int* tmp = in; in = out; out = tmp;
  }
  for (int i = t; i < 512; i += 256) bsum[i] = (i == 0) ? 0 : in[i - 1];
}

// per-block inclusive scan of deg + block offset -> rowPtr (exclusive), fused invdeg
__global__ __launch_bounds__(256) void rowptr_k(const int* __restrict__ deg,
                                                const int* __restrict__ bsumEx,
                                                int* __restrict__ rowPtr,
                                                float* __restrict__ invdeg) {
  __shared__ int a[256], b[256];
  int t = threadIdx.x;
  int i = blockIdx.x * 256 + t;
  int d = deg[i];
  a[t] = d;
  __syncthreads();
  int* in = a;
  int* out = b;
  for (int st = 1; st < 256; st <<= 1) {
    out[t] = in[t] + (t >= st ? in[t - st] : 0);
    __syncthreads();
    int* tmp = in; in = out; out = tmp;
  }
  int incl = in[t] + bsumEx[blockIdx.x];
  rowPtr[i + 1] = incl;
  invdeg[i] = 1.0f / fmaxf((float)d, 1.0f);
  if (i == 0) rowPtr[0] = 0;
}

// Per-sub LDS counting scatter; sequential read preserves src-sorted order.
#define CSR_CAP 12032
__global__ __launch_bounds__(256) void scat4_k(const unsigned int* __restrict__ bkt,
                                               const int* __restrict__ sbase,
                                               const int* __restrict__ rowPtr,
                                               int* __restrict__ csr) {
  __shared__ int cur[512];
  __shared__ int cbuf[CSR_CAP];
  const int t = threadIdx.x;
  const int i = blockIdx.x;
  const int node0 = i * 512;
  const int base0 = rowPtr[node0];
  cur[t] = rowPtr[node0 + t] - base0;
  cur[t + 256] = rowPtr[node0 + t + 256] - base0;
  __syncthreads();
  const int lo = sbase[i], hi = sbase[i + 1];
  for (int e = lo + t; e < hi; e += 256) {
    unsigned v = bkt[e];
    int pos = atomicAdd(&cur[v >> 17], 1);
    int sval = (int)(v & 0x1FFFFu);
    if (pos < CSR_CAP) cbuf[pos] = sval;
    else csr[base0 + pos] = sval;   // never taken for uniform-random input
  }
  __syncthreads();
  const int cnt = rowPtr[node0 + 512] - base0;
  const int lim = cnt < CSR_CAP ? cnt : CSR_CAP;
  for (int idx = t; idx < lim; idx += 256) csr[base0 + idx] = cbuf[idx];
}

// ---- per-edge packed (src 17b | graph 6b | deg 9b) in src-sorted order.
__global__ __launch_bounds__(256) void epb_k(const int* __restrict__ srcS,
                                             const int* __restrict__ dstS,
                                             const int* __restrict__ deg,
                                             unsigned int* __restrict__ ep, int E) {
  int e = blockIdx.x * 256 + threadIdx.x;
  if (e >= E) return;
  int s = srcS[e];
  int d = dstS[e];
  unsigned dg = (unsigned)min(deg[d], 511);
  ep[e] = (unsigned)s | ((unsigned)(d >> 11) << 17) | (dg << 23);
}

// ---- conv1 MFMA GEMM (LDS-free, round-18 structure).
// out1 = fp8_e4m3(x @ W1l.T) ; out2 = fp32(b1l + x @ W1r.T)
__global__ __launch_bounds__(256) void gemm1_k(const float4* __restrict__ x4,
                                               const unsigned short* __restrict__ wb1,
                                               const unsigned short* __restrict__ wb2,
                                               const float* __restrict__ bias2,
                                               unsigned char* __restrict__ out1,
                                               float* __restrict__ out2) {
  constexpr int K = 128, K4 = K / 4;
  const int t = threadIdx.x;
  const int lane = t & 63;
  const int wv = t >> 6;
  const int col = lane & 15;
  const int quad = lane >> 4;
  const int nb = blockIdx.x * 64;
  const int arow = nb + wv * 16 + col;   // A-fragment row (m = lane&15)
  f32x4v acc1[4], acc2[4];
#pragma unroll
  for (int ct = 0; ct < 4; ct++) {
    acc1[ct] = (f32x4v){0.f, 0.f, 0.f, 0.f};
    float bj = bias2[ct * 16 + col];
    acc2[ct] = (f32x4v){bj, bj, bj, bj};
  }
#pragma unroll
  for (int s = 0; s < K / 32; s++) {
    float4 f0 = x4[(size_t)arow * K4 + s * 8 + quad * 2];
    float4 f1 = x4[(size_t)arow * K4 + s * 8 + quad * 2 + 1];
    unsigned short h[8];
    h[0] = f2bf(f0.x); h[1] = f2bf(f0.y); h[2] = f2bf(f0.z); h[3] = f2bf(f0.w);
    h[4] = f2bf(f1.x); h[5] = f2bf(f1.y); h[6] = f2bf(f1.z); h[7] = f2bf(f1.w);
    bf16x8 a = *(const bf16x8*)h;
#pragma unroll
    for (int ct = 0; ct < 4; ct++) {
      bf16x8 b1 = *(const bf16x8*)&wb1[(size_t)((s * 4 + ct) * 64 + lane) * 8];
      acc1[ct] = __builtin_amdgcn_mfma_f32_16x16x32_bf16(a, b1, acc1[ct], 0, 0, 0);
      bf16x8 b2 = *(const bf16x8*)&wb2[(size_t)((s * 4 + ct) * 64 + lane) * 8];
      acc2[ct] = __builtin_amdgcn_mfma_f32_16x16x32_bf16(a, b2, acc2[ct], 0, 0, 0);
    }
  }
#pragma unroll
  for (int ct = 0; ct < 4; ct++) {
#pragma unroll
    for (int reg = 0; reg < 4; reg++) {
      int node = nb + wv * 16 + quad * 4 + reg;
      unsigned pk = (unsigned)__builtin_amdgcn_cvt_pk_fp8_f32(acc1[ct][reg],
                                                              acc1[ct][reg], 0, false);
      out1[(size_t)node * 64 + ct * 16 + col] = (unsigned char)(pk & 0xff);
      out2[(size_t)node * 64 + ct * 16 + col] = acc2[ct][reg];
    }
  }
}

// ---- fused gather + conv2 GEMM (round-19 structure, proven correct) ----
// h1 = bf16(gather(y1)*inv + xr) in wave-local LDS; y2 = fp8(h1@W2l.T); p1
// graph-mean partials. gmean2 is computed by push2_k below.
#define LROW 72
__global__ __launch_bounds__(256) void gatherf_k(const uint4* __restrict__ yb,
                                                 const int* __restrict__ csr,
                                                 const int* __restrict__ rowPtr,
                                                 const float* __restrict__ invdeg,
                                                 const float4* __restrict__ xr,
                                                 const unsigned short* __restrict__ wb2,
                                                 unsigned char* __restrict__ y2,
                                                 float* __restrict__ pm) {
  __shared__ float sg[4][4][16];
  __shared__ unsigned short sh1[64 * LROW];
  const int t = threadIdx.x;
  const int lane = t & 63;
  const int wv = t >> 6;
  const int q = lane & 3;     // 16-B quarter of the 64-B row
  const int nl = lane >> 2;   // node within wave (0..15)
  const int nb = blockIdx.x * 64;   // 64 nodes per block (4 waves x 16)
  const int n = nb + wv * 16 + nl;
  const int rp0 = rowPtr[n], rp1 = rowPtr[n + 1];
  float acc[16];
#pragma unroll
  for (int k = 0; k < 16; k++) acc[k] = 0.f;
  for (int e = rp0; e < rp1; e++) {
    int s = csr[e];
    uint4 v = yb[(size_t)s * 4 + q];
    f32x2 p;
    p = __builtin_amdgcn_cvt_pk_f32_fp8(v.x, false); acc[0] += p.x;  acc[1] += p.y;
    p = __builtin_amdgcn_cvt_pk_f32_fp8(v.x, true);  acc[2] += p.x;  acc[3] += p.y;
    p = __builtin_amdgcn_cvt_pk_f32_fp8(v.y, false); acc[4] += p.x;  acc[5] += p.y;
    p = __builtin_amdgcn_cvt_pk_f32_fp8(v.y, true);  acc[6] += p.x;  acc[7] += p.y;
    p = __builtin_amdgcn_cvt_pk_f32_fp8(v.z, false); acc[8] += p.x;  acc[9] += p.y;
    p = __builtin_amdgcn_cvt_pk_f32_fp8(v.z, true);  acc[10] += p.x; acc[11] += p.y;
    p = __builtin_amdgcn_cvt_pk_f32_fp8(v.w, false); acc[12] += p.x; acc[13] += p.y;
    p = __builtin_amdgcn_cvt_pk_f32_fp8(v.w, true);  acc[14] += p.x; acc[15] += p.y;
  }
  const float sc = invdeg[n];
  float gacc[16];
  {
    const int nloc = wv * 16 + nl;
    unsigned short hh[16];
#pragma unroll
    for (int u = 0; u < 4; u++) {
      float4 o = xr[(size_t)n * 16 + q * 4 + u];
      float v0 = acc[4 * u + 0] * sc + o.x;
      float v1 = acc[4 * u + 1] * sc + o.y;
      float v2 = acc[4 * u + 2] * sc + o.z;
      float v3 = acc[4 * u + 3] * sc + o.w;
      gacc[4 * u + 0] = v0; gacc[4 * u + 1] = v1;
      gacc[4 * u + 2] = v2; gacc[4 * u + 3] = v3;
      hh[4 * u + 0] = f2bf(v0); hh[4 * u + 1] = f2bf(v1);
      hh[4 * u + 2] = f2bf(v2); hh[4 * u + 3] = f2bf(v3);
    }
    *(uint4*)&sh1[nloc * LROW + q * 16] = *(uint4*)&hh[0];
    *(uint4*)&sh1[nloc * LROW + q * 16 + 8] = *(uint4*)&hh[8];
  }
  // reduce across the wave's 16 nodes (lane bits 2..5) — ALL lanes active, uniform
#pragma unroll
  for (int m = 4; m <= 32; m <<= 1)
#pragma unroll
    for (int k = 0; k < 16; k++) gacc[k] += __shfl_xor(gacc[k], m, 64);
  if (nl == 0) {
#pragma unroll
    for (int k = 0; k < 16; k++) sg[wv][q][k] = gacc[k];
  }
  __syncthreads();
  if (t < 64) {
    int qq = t >> 4, k = t & 15;
    float tot = sg[0][qq][k] + sg[1][qq][k] + sg[2][qq][k] + sg[3][qq][k];
    pm[((size_t)(blockIdx.x >> 5) * 32 + (blockIdx.x & 31)) * 64 + t] = tot;
  }
  {
    // phase B: y2 = fp8(h1 @ W2l.T), A from this wave's own LDS rows
    const int col = lane & 15;
    const int quad = lane >> 4;
    f32x4v a2[4];
#pragma unroll
    for (int ct = 0; ct < 4; ct++) a2[ct] = (f32x4v){0.f, 0.f, 0.f, 0.f};
#pragma unroll
    for (int s = 0; s < 2; s++) {
      bf16x8 a = *(const bf16x8*)&sh1[(wv * 16 + col) * LROW + s * 32 + quad * 8];
#pragma unroll
      for (int ct = 0; ct < 4; ct++) {
        bf16x8 b = *(const bf16x8*)&wb2[(size_t)((s * 4 + ct) * 64 + lane) * 8];
        a2[ct] = __builtin_amdgcn_mfma_f32_16x16x32_bf16(a, b, a2[ct], 0, 0, 0);
      }
    }
#pragma unroll
    for (int ct = 0; ct < 4; ct++) {
#pragma unroll
      for (int reg = 0; reg < 4; reg++) {
        int node = nb + wv * 16 + quad * 4 + reg;
        unsigned pk = (unsigned)__builtin_amdgcn_cvt_pk_fp8_f32(a2[ct][reg],
                                                                a2[ct][reg], 0, false);
        y2[(size_t)node * 64 + ct * 16 + col] = (unsigned char)(pk & 0xff);
      }
    }
  }
}

// ---- conv2 aggregation as src-major PUSH over src-sorted edges ----
// Round-9 post-mortem: atomicAdd(float) on LDS compiles to a CAS retry loop
// (no native fp add without unsafe-fp-atomics) -> 669us at 1.5% VALU. Fix:
// unsafeAtomicAdd emits native ds_add_f32 (fire-and-forget, ~6cyc). Also
// grid 512->1024 (4 blocks/CU, 50% occ) and 2 wave-parity LDS tables to
// halve cross-wave same-address collisions.
#define P2B 1024
__global__ __launch_bounds__(256) void push2_k(const uint4* __restrict__ yb,
                                               const unsigned int* __restrict__ ep,
                                               float* __restrict__ pp, int E) {
  __shared__ float acc[2][64 * 65];
  const int t = threadIdx.x;
  float* tab = acc[(t >> 6) & 1];
  for (int i = t; i < 2 * 64 * 65; i += 256) ((float*)acc)[i] = 0.f;
  __syncthreads();
  const int epb = (E + P2B - 1) / P2B;   // 2048
  const int lo = blockIdx.x * epb;
  const int hi = min(E, lo + epb);
  const int q = t & 3;
  for (int e = lo + (t >> 2); e < hi; e += 64) {
    unsigned v = ep[e];
    int srcn = (int)(v & 0x1FFFFu);
    int g = (int)((v >> 17) & 63u);
    float w = 1.0f / fmaxf((float)(v >> 23), 1.0f);
    uint4 y = yb[(size_t)srcn * 4 + q];
    float* a = &tab[g * 65 + q * 16];
    f32x2 p;
    p = __builtin_amdgcn_cvt_pk_f32_fp8(y.x, false); unsafeAtomicAdd(a + 0, p.x * w);  unsafeAtomicAdd(a + 1, p.y * w);
    p = __builtin_amdgcn_cvt_pk_f32_fp8(y.x, true);  unsafeAtomicAdd(a + 2, p.x * w);  unsafeAtomicAdd(a + 3, p.y * w);
    p = __builtin_amdgcn_cvt_pk_f32_fp8(y.y, false); unsafeAtomicAdd(a + 4, p.x * w);  unsafeAtomicAdd(a + 5, p.y * w);
    p = __builtin_amdgcn_cvt_pk_f32_fp8(y.y, true);  unsafeAtomicAdd(a + 6, p.x * w);  unsafeAtomicAdd(a + 7, p.y * w);
    p = __builtin_amdgcn_cvt_pk_f32_fp8(y.z, false); unsafeAtomicAdd(a + 8, p.x * w);  unsafeAtomicAdd(a + 9, p.y * w);
    p = __builtin_amdgcn_cvt_pk_f32_fp8(y.z, true);  unsafeAtomicAdd(a + 10, p.x * w); unsafeAtomicAdd(a + 11, p.y * w);
    p = __builtin_amdgcn_cvt_pk_f32_fp8(y.w, false); unsafeAtomicAdd(a + 12, p.x * w); unsafeAtomicAdd(a + 13, p.y * w);
    p = __builtin_amdgcn_cvt_pk_f32_fp8(y.w, true);  unsafeAtomicAdd(a + 14, p.x * w); unsafeAtomicAdd(a + 15, p.y * w);
  }
  __syncthreads();
  for (int i = t; i < 4096; i += 256) {
    int row = i >> 6, col = i & 63;
    pp[(size_t)blockIdx.x * 4096 + i] = acc[0][row * 65 + col] + acc[1][row * 65 + col];
  }
}

// gmean2[g][j] = (1/2048) * sum_blk pp[blk][g*64+j]
__global__ __launch_bounds__(256) void reduce2_k(const float* __restrict__ pp,
                                                 float* __restrict__ gm) {
  int idx = blockIdx.x * 256 + threadIdx.x;   // 4096
  float s = 0.0f;
  for (int b = 0; b < P2B; b++) s += pp[(size_t)b * 4096 + idx];
  gm[idx] = s * (1.0f / 2048.0f);
}

// ---- deterministic partial reduce: gm[b][j] = (1/2048) * sum_blk pm[b][blk][j] ----
__global__ __launch_bounds__(256) void reduce_part_k(const float* __restrict__ pm,
                                                     float* __restrict__ gm) {
  int idx = blockIdx.x * 256 + threadIdx.x;   // 4096
  int b = idx >> 6, j = idx & 63;
  float acc = 0.0f;
  for (int blk = 0; blk < 32; blk++) acc += pm[((size_t)b * 32 + blk) * 64 + j];
  gm[idx] = acc * (1.0f / 2048.0f);
}

// ---- g[b][j] = gmean2[b][j] + b2l[j] + sum_k gmean1[b][k] * W2r[j][k] ----
__global__ __launch_bounds__(256) void combine_k(const float* __restrict__ gmean2,
                                                 const float* __restrict__ gmean1,
                                                 const float* __restrict__ b2l,
                                                 const float* __restrict__ W2r,
                                                 float* __restrict__ g) {
  int idx = blockIdx.x * 256 + threadIdx.x;   // 4096
  int b = idx >> 6, j = idx & 63;
  const float4* m4 = (const float4*)(gmean1 + b * 64);
  const float4* w4 = (const float4*)(W2r + j * 64);
  float acc = gmean2[idx] + b2l[j];
#pragma unroll
  for (int k4 = 0; k4 < 16; k4++) {
    float4 mv = m4[k4], wv = w4[k4];
    acc += mv.x * wv.x + mv.y * wv.y + mv.z * wv.z + mv.w * wv.w;
  }
  g[idx] = acc;
}

// ---- h = relu(g @ fc1_W.T + fc1_b)   g:[64,64] fc1_W:[128,64] -> h:[64,128] ----
__global__ __launch_bounds__(256) void mlp1_k(const float* __restrict__ g,
                                              const float* __restrict__ fc1_W,
                                              const float* __restrict__ fc1_b,
                                              float* __restrict__ h) {
  int idx = blockIdx.x * 256 + threadIdx.x;
  int b = idx >> 7, k = idx & 127;
  const float4* g4 = (const float4*)(g + b * 64);
  const float4* w4 = (const float4*)(fc1_W + k * 64);
  float acc = fc1_b[k];
#pragma unroll
  for (int j4 = 0; j4 < 16; j4++) {
    float4 gv = g4[j4], wv = w4[j4];
    acc += gv.x * wv.x + gv.y * wv.y + gv.z * wv.z + gv.w * wv.w;
  }
  h[idx] = fmaxf(acc, 0.0f);
}

// ---- q = h @ fc2_W.T + fc2_b   h:[64,128] fc2_W:[2048,128] -> q:[64,2048] ----
__global__ __launch_bounds__(256) void mlp2_k(const float* __restrict__ h,
                                              const float* __restrict__ fc2_W,
                                              const float* __restrict__ fc2_b,
                                              float* __restrict__ out) {
  __shared__ float4 sh[32];
  int b = blockIdx.x >> 3;
  int a = (blockIdx.x & 7) * 256 + threadIdx.x;
  if (threadIdx.x < 32) sh[threadIdx.x] = ((const float4*)(h + b * 128))[threadIdx.x];
  __syncthreads();
  const float4* w4 = (const float4*)(fc2_W + (size_t)a * 128);
  float acc = fc2_b[a];
#pragma unroll
  for (int k4 = 0; k4 < 32; k4++) {
    float4 hv = sh[k4], wv = w4[k4];
    acc += hv.x * wv.x + hv.y * wv.y + hv.z * wv.z + hv.w * wv.w;
  }
  out[b * 2048 + a] = acc;
}

extern "C" void kernel_launch(void* const* d_in, const int* in_sizes, int n_in,
                              void* d_out, int out_size, void* d_ws, size_t ws_size,
                              hipStream_t stream) {
  const float* x     = (const float*)d_in[0];
  const int*   ei    = (const int*)d_in[1];
  const float* W1l   = (const float*)d_in[2];
  const float* b1l   = (const float*)d_in[3];
  const float* W1r   = (const float*)d_in[4];
  const float* W2l   = (const float*)d_in[5];
  const float* b2l   = (const float*)d_in[6];
  const float* W2r   = (const float*)d_in[7];
  const float* fc1_W = (const float*)d_in[8];
  const float* fc1_b = (const float*)d_in[9];
  const float* fc2_W = (const float*)d_in[10];
  const float* fc2_b = (const float*)d_in[11];
  float* out = (float*)d_out;

  const int N = in_sizes[0] / D_IN;   // 131072
  const int E = in_sizes[1] / 2;      // 2097152
  const int* src = ei;
  const int* dst = ei + E;

  // workspace layout (~69 MiB; 78 MiB proven available)
  char* ws = (char*)d_ws;
  int*   deg    = (int*)ws;     ws += (size_t)N * 4;
  int*   rowPtr = (int*)ws;     ws += (size_t)(N + 256) * 4;
  int*   bsum   = (int*)ws;     ws += 512 * 4;
  float* invdeg = (float*)ws;   ws += (size_t)N * 4;
  float* gmean1 = (float*)ws;   ws += 4096 * 4;
  float* gmean2 = (float*)ws;   ws += 4096 * 4;
  float* g      = (float*)ws;   ws += 4096 * 4;
  float* hbuf   = (float*)ws;   ws += 8192 * 4;
  unsigned short* wb1l = (unsigned short*)ws;  ws += 8192 * 2;  // mfma-packed bf16
  unsigned short* wb1r = (unsigned short*)ws;  ws += 8192 * 2;
  unsigned short* wb2l = (unsigned short*)ws;  ws += 4096 * 2;
  int*   sh     = (int*)ws;     ws += (size_t)256 * 1024 * 4;  // pass-0 [bin][chunk]
  int*   bh     = (int*)ws;     ws += (size_t)256 * 1024 * 4;  // pass-1 [bin][chunk]
  int*   tot    = (int*)ws;     ws += 256 * 4;
  int*   ssub   = (int*)ws;     ws += 260 * 4;    // src-bucket starts [257]
  int*   sbase  = (int*)ws;     ws += 260 * 4;    // dst-sub starts [257]
  float* p1     = (float*)ws;   ws += (size_t)64 * 32 * 64 * 4;  // graph-mean partials
  unsigned int* bkt = (unsigned int*)ws;  ws += (size_t)E * 4;   // sub-binned edges / ep
  int*   csr    = (int*)ws;     ws += (size_t)E * 4;
  unsigned char* bufA = (unsigned char*)ws;  ws += (size_t)64 * N;      // y1 fp8
  unsigned char* bufD = (unsigned char*)ws;  ws += (size_t)64 * N;      // y2 fp8
  float* bufB   = (float*)ws;   ws += (size_t)64 * N * 4;  // xr (fp32)
  size_t used = (size_t)(ws - (char*)d_ws);

  // Aliases (temporally disjoint):
  //   srcS -> bufD (read by bfill1 + epb_k; bufD written later by gatherf)
  //   dstS -> bufA (read by bhist1/bfill1 + epb_k; bufA written later by gemm1)
  //   ep   -> bkt  (bkt dead after scat4; ep written by epb_k, read by push2)
  //   pp   -> bufB (xr dead after gatherf; pp = 16MB <= bufB 32MB)
  int* srcS = (int*)bufD;
  int* dstS = (int*)bufA;
  unsigned int* ep = bkt;
  float* pp = bufB;

  // Zero the ENTIRE used workspace every call (round-10 fix: every call must
  // start from the identical, validated-benign state; ~11 us at HBM write BW).
  hipMemsetAsync(d_ws, 0, used, stream);

  wprep_mfma_k<<<4, 256, 0, stream>>>(W1l, wb1l, 128);
  wprep_mfma_k<<<4, 256, 0, stream>>>(W1r, wb1r, 128);
  wprep_mfma_k<<<2, 256, 0, stream>>>(W2l, wb2l, 64);

  // CSR build: pass-0 coarse src-sort, pass-1 dst-sub sort (order-preserving
  // at chunk level), then per-sub LDS histogram + counting scatter.
  const int nch = (E + 2047) >> 11;   // 1024 for E=2M (hist rows sized 1024)
  bhist1_k<<<nch, 256, 0, stream>>>(src, sh, E);
  scanA_k<<<256, 256, 0, stream>>>(sh, tot);
  scanB_k<<<1, 256, 0, stream>>>(tot, ssub);
  sfill_k<<<nch, 256, 0, stream>>>(src, dst, sh, ssub, srcS, dstS, E);
  bhist1_k<<<nch, 256, 0, stream>>>(dstS, bh, E);
  scanA_k<<<256, 256, 0, stream>>>(bh, tot);
  scanB_k<<<1, 256, 0, stream>>>(tot, sbase);
  bfill1_k<<<nch, 256, 0, stream>>>(srcS, dstS, bh, sbase, bkt, E);
  deg4_k<<<256, 256, 0, stream>>>(bkt, sbase, deg);
  blocksum_k<<<N / 256, 256, 0, stream>>>(deg, bsum);
  scanbsum_k<<<1, 256, 0, stream>>>(bsum);
  rowptr_k<<<N / 256, 256, 0, stream>>>(deg, bsum, rowPtr, invdeg);
  scat4_k<<<256, 256, 0, stream>>>(bkt, sbase, rowPtr, csr);
  // pack per-edge (src|graph|deg) for the conv2 push (bkt -> ep reuse)
  epb_k<<<(E + 255) / 256, 256, 0, stream>>>(srcS, dstS, deg, ep, E);

  // conv1: y1 = fp8(x@W1l.T) -> bufA ; xr = b1l + x@W1r.T -> bufB (fp32)
  gemm1_k<<<N / 64, 256, 0, stream>>>((const float4*)x, wb1l, wb1r, b1l, bufA, bufB);
  // FUSED: h1 = bf16(gather(y1)*inv + xr) in LDS ; y2 = fp8(h1@W2l.T) -> bufD ;
  // p1 partials (fp32)
  gatherf_k<<<N / 64, 256, 0, stream>>>((const uint4*)bufA, csr, rowPtr, invdeg,
                                        (const float4*)bufB, wb2l, bufD, p1);
  reduce_part_k<<<16, 256, 0, stream>>>(p1, gmean1);

  // conv2 aggregation: src-major push over src-sorted edges (replaces gather<0>)
  push2_k<<<P2B, 256, 0, stream>>>((const uint4*)bufD, ep, pp, E);
  reduce2_k<<<16, 256, 0, stream>>>(pp, gmean2);

  // g = gmean2 + b2l + gmean1 @ W2r.T
  combine_k<<<16, 256, 0, stream>>>(gmean2, gmean1, b2l, W2r, g);
  mlp1_k<<<32, 256, 0, stream>>>(g, fc1_W, fc1_b, hbuf);
  mlp2_k<<<512, 256, 0, stream>>>(hbuf, fc2_W, fc2_b, out);
}

// Round 11
// 352.610 us; speedup vs baseline: 2.9461x; 2.9461x over previous
//
#include <hip/hip_runtime.h>
#include <hip/hip_bf16.h>

#define D_IN 128
#define D_EMB 64

typedef float f32x2 __attribute__((ext_vector_type(2)));
typedef float f32x4v __attribute__((ext_vector_type(4)));
typedef short bf16x8 __attribute__((ext_vector_type(8)));   // 8 bf16 = 4 VGPRs (guide §3)

static __device__ __forceinline__ unsigned short f2bf(float f) {
  __hip_bfloat16 h = __float2bfloat16(f);
  return *(unsigned short*)&h;
}

// ---- MFMA weight prep: W[64][K] fp32 -> packed bf16 B-fragments.
// frag index tid=(s*4+ct)*64+lane holds W[ct*16+(lane&15)][s*32+(lane>>4)*8 + j], j=0..7
__global__ __launch_bounds__(256) void wprep_mfma_k(const float* __restrict__ W,
                                                    unsigned short* __restrict__ out,
                                                    int K) {
  int tid = blockIdx.x * 256 + threadIdx.x;
  int total = (K / 32) * 4 * 64;
  if (tid >= total) return;
  int lane = tid & 63;
  int ct = (tid >> 6) & 3;
  int s = tid >> 8;
  int row = ct * 16 + (lane & 15);
  int kk = s * 32 + (lane >> 4) * 8;
  unsigned short tmp[8];
#pragma unroll
  for (int j = 0; j < 8; j++) tmp[j] = f2bf(W[row * K + kk + j]);
  *(uint4*)&out[(size_t)tid * 8] = *(uint4*)tmp;
}

// ==== CSR build (round-17 design, proven): src-sort pass 0 + dst-sub sort ====

// Per-chunk 256-bin histogram of key>>9, written TRANSPOSED h[bin*1024+chunk].
__global__ __launch_bounds__(256) void bhist1_k(const int* __restrict__ key,
                                                int* __restrict__ bh, int E) {
  __shared__ int h[256];
  const int t = threadIdx.x;
  h[t] = 0;
  __syncthreads();
  const int base = blockIdx.x * 2048;
#pragma unroll
  for (int j = 0; j < 8; j++) {
    int e = base + j * 256 + t;
    if (e < E) atomicAdd(&h[key[e] >> 9], 1);
  }
  __syncthreads();
  bh[t * 1024 + blockIdx.x] = h[t];
}

// Per-bin exclusive scan over the 1024 chunks (one block per bin), in place.
__global__ __launch_bounds__(256) void scanA_k(int* __restrict__ bh,
                                               int* __restrict__ bintot) {
  __shared__ int sa[256], sb[256];
  const int t = threadIdx.x;
  int* row = bh + (size_t)blockIdx.x * 1024;
  int v0 = row[t * 4], v1 = row[t * 4 + 1], v2 = row[t * 4 + 2], v3 = row[t * 4 + 3];
  int sum = v0 + v1 + v2 + v3;
  sa[t] = sum;
  __syncthreads();
  int* in = sa;
  int* out = sb;
  for (int st = 1; st < 256; st <<= 1) {
    out[t] = in[t] + (t >= st ? in[t - st] : 0);
    __syncthreads();
    int* tmp = in; in = out; out = tmp;
  }
  int excl = in[t] - sum;
  row[t * 4] = excl;
  row[t * 4 + 1] = excl + v0;
  row[t * 4 + 2] = excl + v0 + v1;
  row[t * 4 + 3] = excl + v0 + v1 + v2;
  if (t == 255) bintot[blockIdx.x] = in[255];
}

// Exclusive scan of the 256 bin totals -> base[256] bucket starts, base[256]=E.
__global__ __launch_bounds__(256) void scanB_k(const int* __restrict__ bintot,
                                               int* __restrict__ base) {
  __shared__ int sa[256], sb[256];
  const int t = threadIdx.x;
  int v = bintot[t];
  sa[t] = v;
  __syncthreads();
  int* in = sa;
  int* out = sb;
  for (int st = 1; st < 256; st <<= 1) {
    out[t] = in[t] + (t >= st ? in[t - st] : 0);
    __syncthreads();
    int* tmp = in; in = out; out = tmp;
  }
  base[t] = in[t] - v;
  if (t == 255) base[256] = in[255];
}

// Pass-0 fill: LDS chunk counting-sort by src>>9, emits parallel (srcS, dstS).
__global__ __launch_bounds__(256) void sfill_k(const int* __restrict__ src,
                                               const int* __restrict__ dst,
                                               const int* __restrict__ sh,
                                               const int* __restrict__ ssub,
                                               int* __restrict__ srcS,
                                               int* __restrict__ dstS, int E) {
  __shared__ int hA[256], hB[256], runCur[256], gb[256];
  __shared__ int scache[2048];
  __shared__ int dcache[2048];
  __shared__ int sortS[2048];
  __shared__ int sortD[2048];
  __shared__ unsigned short subb[2048];
  const int t = threadIdx.x;
  const int base = blockIdx.x * 2048;
  const int n = min(2048, E - base);
  hA[t] = 0;
  __syncthreads();
#pragma unroll
  for (int j = 0; j < 8; j++) {
    int idx = j * 256 + t;
    int e = base + idx;
    if (idx < n) {
      int s = src[e];
      scache[idx] = s;
      dcache[idx] = dst[e];
      atomicAdd(&hA[s >> 9], 1);
    }
  }
  __syncthreads();
  int cnt = hA[t];
  int* in = hA;
  int* out = hB;
  for (int st = 1; st < 256; st <<= 1) {
    out[t] = in[t] + (t >= st ? in[t - st] : 0);
    __syncthreads();
    int* tmp = in; in = out; out = tmp;
  }
  int rs = in[t] - cnt;
  __syncthreads();
  hB[t] = rs;
  runCur[t] = rs;
  gb[t] = ssub[t] + sh[t * 1024 + blockIdx.x];
  __syncthreads();
#pragma unroll
  for (int j = 0; j < 8; j++) {
    int idx = j * 256 + t;
    if (idx < n) {
      int s = scache[idx];
      int b = s >> 9;
      int lpos = atomicAdd(&runCur[b], 1);
      sortS[lpos] = s;
      sortD[lpos] = dcache[idx];
      subb[lpos] = (unsigned short)b;
    }
  }
  __syncthreads();
  for (int idx = t; idx < n; idx += 256) {
    int b = subb[idx];
    int g = gb[b] + idx - hB[b];
    srcS[g] = sortS[idx];
    dstS[g] = sortD[idx];
  }
}

// Pass-1 fill: LDS chunk counting-sort by dst>>9 reading the src-sorted
// arrays (stable at chunk level -> dst-sub entries stay src-ordered).
// Packed word: (dst&511)<<17 | src  (9b node-in-sub + 17b src, N=2^17).
__global__ __launch_bounds__(256) void bfill1_k(const int* __restrict__ src,
                                                const int* __restrict__ dst,
                                                const int* __restrict__ bh,
                                                const int* __restrict__ sbase,
                                                unsigned int* __restrict__ bkt,
                                                int E) {
  __shared__ int hA[256], hB[256], runCur[256], gb[256];
  __shared__ int dcache[2048];
  __shared__ unsigned int sorted[2048];
  __shared__ unsigned short subb[2048];
  const int t = threadIdx.x;
  const int base = blockIdx.x * 2048;
  const int n = min(2048, E - base);
  hA[t] = 0;
  __syncthreads();
#pragma unroll
  for (int j = 0; j < 8; j++) {
    int idx = j * 256 + t;
    int e = base + idx;
    if (idx < n) {
      int d = dst[e];
      dcache[idx] = d;
      atomicAdd(&hA[d >> 9], 1);
    }
  }
  __syncthreads();
  int cnt = hA[t];
  int* in = hA;
  int* out = hB;
  for (int st = 1; st < 256; st <<= 1) {
    out[t] = in[t] + (t >= st ? in[t - st] : 0);
    __syncthreads();
    int* tmp = in; in = out; out = tmp;
  }
  int rs = in[t] - cnt;
  __syncthreads();
  hB[t] = rs;
  runCur[t] = rs;
  gb[t] = sbase[t] + bh[t * 1024 + blockIdx.x];
  __syncthreads();
#pragma unroll
  for (int j = 0; j < 8; j++) {
    int idx = j * 256 + t;
    int e = base + idx;
    if (idx < n) {
      int d = dcache[idx];
      int b = d >> 9;
      int lpos = atomicAdd(&runCur[b], 1);
      sorted[lpos] = ((unsigned)(d & 511) << 17) | (unsigned)src[e];
      subb[lpos] = (unsigned short)b;
    }
  }
  __syncthreads();
  for (int idx = t; idx < n; idx += 256) {
    int b = subb[idx];
    bkt[gb[b] + idx - hB[b]] = sorted[idx];
  }
}

// Per-sub degree count (own contiguous sub-bucket, 32 iters, atomic-free write).
__global__ __launch_bounds__(256) void deg4_k(const unsigned int* __restrict__ bkt,
                                              const int* __restrict__ sbase,
                                              int* __restrict__ deg) {
  __shared__ int h[512];
  const int t = threadIdx.x;
  h[t] = 0;
  h[t + 256] = 0;
  __syncthreads();
  const int i = blockIdx.x;
  const int lo = sbase[i], hi = sbase[i + 1];
  for (int e = lo + t; e < hi; e += 256) atomicAdd(&h[bkt[e] >> 17], 1);
  __syncthreads();
  deg[i * 512 + t] = h[t];
  deg[i * 512 + t + 256] = h[t + 256];
}

__global__ __launch_bounds__(256) void blocksum_k(const int* __restrict__ deg,
                                                  int* __restrict__ bsum) {
  __shared__ int sm[256];
  int t = threadIdx.x;
  sm[t] = deg[blockIdx.x * 256 + t];
  __syncthreads();
  for (int s = 128; s > 0; s >>= 1) {
    if (t < s) sm[t] += sm[t + s];
    __syncthreads();
  }
  if (t == 0) bsum[blockIdx.x] = sm[0];
}

// single block: exclusive scan of 512 block sums (in place)
__global__ __launch_bounds__(256) void scanbsum_k(int* __restrict__ bsum) {
  __shared__ int a[512], b[512];
  int t = threadIdx.x;
  a[t] = bsum[t];
  a[t + 256] = bsum[t + 256];
  __syncthreads();
  int* in = a;
  int* out = b;
  for (int st = 1; st < 512; st <<= 1) {
    for (int i = t; i < 512; i += 256) out[i] = in[i] + (i >= st ? in[i - st] : 0);
    __syncthreads();
    int* tmp = in; in = out; out = tmp;
  }
  for (int i = t; i < 512; i += 256) bsum[i] = (i == 0) ? 0 : in[i - 1];
}

// per-block inclusive scan of deg + block offset -> rowPtr (exclusive), fused invdeg
__global__ __launch_bounds__(256) void rowptr_k(const int* __restrict__ deg,
                                                const int* __restrict__ bsumEx,
                                                int* __restrict__ rowPtr,
                                                float* __restrict__ invdeg) {
  __shared__ int a[256], b[256];
  int t = threadIdx.x;
  int i = blockIdx.x * 256 + t;
  int d = deg[i];
  a[t] = d;
  __syncthreads();
  int* in = a;
  int* out = b;
  for (int st = 1; st < 256; st <<= 1) {
    out[t] = in[t] + (t >= st ? in[t - st] : 0);
    __syncthreads();
    int* tmp = in; in = out; out = tmp;
  }
  int incl = in[t] + bsumEx[blockIdx.x];
  rowPtr[i + 1] = incl;
  invdeg[i] = 1.0f / fmaxf((float)d, 1.0f);
  if (i == 0) rowPtr[0] = 0;
}

// Per-sub LDS counting scatter; sequential read preserves src-sorted order.
#define CSR_CAP 12032
__global__ __launch_bounds__(256) void scat4_k(const unsigned int* __restrict__ bkt,
                                               const int* __restrict__ sbase,
                                               const int* __restrict__ rowPtr,
                                               int* __restrict__ csr) {
  __shared__ int cur[512];
  __shared__ int cbuf[CSR_CAP];
  const int t = threadIdx.x;
  const int i = blockIdx.x;
  const int node0 = i * 512;
  const int base0 = rowPtr[node0];
  cur[t] = rowPtr[node0 + t] - base0;
  cur[t + 256] = rowPtr[node0 + t + 256] - base0;
  __syncthreads();
  const int lo = sbase[i], hi = sbase[i + 1];
  for (int e = lo + t; e < hi; e += 256) {
    unsigned v = bkt[e];
    int pos = atomicAdd(&cur[v >> 17], 1);
    int sval = (int)(v & 0x1FFFFu);
    if (pos < CSR_CAP) cbuf[pos] = sval;
    else csr[base0 + pos] = sval;   // never taken for uniform-random input
  }
  __syncthreads();
  const int cnt = rowPtr[node0 + 512] - base0;
  const int lim = cnt < CSR_CAP ? cnt : CSR_CAP;
  for (int idx = t; idx < lim; idx += 256) csr[base0 + idx] = cbuf[idx];
}

// ---- conv1 MFMA GEMM (LDS-free, round-18 structure).
// out1 = fp8_e4m3(x @ W1l.T) ; out2 = fp32(b1l + x @ W1r.T)
__global__ __launch_bounds__(256) void gemm1_k(const float4* __restrict__ x4,
                                               const unsigned short* __restrict__ wb1,
                                               const unsigned short* __restrict__ wb2,
                                               const float* __restrict__ bias2,
                                               unsigned char* __restrict__ out1,
                                               float* __restrict__ out2) {
  constexpr int K = 128, K4 = K / 4;
  const int t = threadIdx.x;
  const int lane = t & 63;
  const int wv = t >> 6;
  const int col = lane & 15;
  const int quad = lane >> 4;
  const int nb = blockIdx.x * 64;
  const int arow = nb + wv * 16 + col;   // A-fragment row (m = lane&15)
  f32x4v acc1[4], acc2[4];
#pragma unroll
  for (int ct = 0; ct < 4; ct++) {
    acc1[ct] = (f32x4v){0.f, 0.f, 0.f, 0.f};
    float bj = bias2[ct * 16 + col];
    acc2[ct] = (f32x4v){bj, bj, bj, bj};
  }
#pragma unroll
  for (int s = 0; s < K / 32; s++) {
    float4 f0 = x4[(size_t)arow * K4 + s * 8 + quad * 2];
    float4 f1 = x4[(size_t)arow * K4 + s * 8 + quad * 2 + 1];
    unsigned short h[8];
    h[0] = f2bf(f0.x); h[1] = f2bf(f0.y); h[2] = f2bf(f0.z); h[3] = f2bf(f0.w);
    h[4] = f2bf(f1.x); h[5] = f2bf(f1.y); h[6] = f2bf(f1.z); h[7] = f2bf(f1.w);
    bf16x8 a = *(const bf16x8*)h;
#pragma unroll
    for (int ct = 0; ct < 4; ct++) {
      bf16x8 b1 = *(const bf16x8*)&wb1[(size_t)((s * 4 + ct) * 64 + lane) * 8];
      acc1[ct] = __builtin_amdgcn_mfma_f32_16x16x32_bf16(a, b1, acc1[ct], 0, 0, 0);
      bf16x8 b2 = *(const bf16x8*)&wb2[(size_t)((s * 4 + ct) * 64 + lane) * 8];
      acc2[ct] = __builtin_amdgcn_mfma_f32_16x16x32_bf16(a, b2, acc2[ct], 0, 0, 0);
    }
  }
#pragma unroll
  for (int ct = 0; ct < 4; ct++) {
#pragma unroll
    for (int reg = 0; reg < 4; reg++) {
      int node = nb + wv * 16 + quad * 4 + reg;
      unsigned pk = (unsigned)__builtin_amdgcn_cvt_pk_fp8_f32(acc1[ct][reg],
                                                              acc1[ct][reg], 0, false);
      out1[(size_t)node * 64 + ct * 16 + col] = (unsigned char)(pk & 0xff);
      out2[(size_t)node * 64 + ct * 16 + col] = acc2[ct][reg];
    }
  }
}

// ---- fused gather + conv2 GEMM (round-19 structure, proven correct) ----
// h1 = bf16(gather(y1)*inv + xr) in wave-local LDS; y2 = fp8(h1@W2l.T); p1
// graph-mean partials.
#define LROW 72
__global__ __launch_bounds__(256) void gatherf_k(const uint4* __restrict__ yb,
                                                 const int* __restrict__ csr,
                                                 const int* __restrict__ rowPtr,
                                                 const float* __restrict__ invdeg,
                                                 const float4* __restrict__ xr,
                                                 const unsigned short* __restrict__ wb2,
                                                 unsigned char* __restrict__ y2,
                                                 float* __restrict__ pm) {
  __shared__ float sg[4][4][16];
  __shared__ unsigned short sh1[64 * LROW];
  const int t = threadIdx.x;
  const int lane = t & 63;
  const int wv = t >> 6;
  const int q = lane & 3;     // 16-B quarter of the 64-B row
  const int nl = lane >> 2;   // node within wave (0..15)
  const int nb = blockIdx.x * 64;   // 64 nodes per block (4 waves x 16)
  const int n = nb + wv * 16 + nl;
  const int rp0 = rowPtr[n], rp1 = rowPtr[n + 1];
  float acc[16];
#pragma unroll
  for (int k = 0; k < 16; k++) acc[k] = 0.f;
  for (int e = rp0; e < rp1; e++) {
    int s = csr[e];
    uint4 v = yb[(size_t)s * 4 + q];
    f32x2 p;
    p = __builtin_amdgcn_cvt_pk_f32_fp8(v.x, false); acc[0] += p.x;  acc[1] += p.y;
    p = __builtin_amdgcn_cvt_pk_f32_fp8(v.x, true);  acc[2] += p.x;  acc[3] += p.y;
    p = __builtin_amdgcn_cvt_pk_f32_fp8(v.y, false); acc[4] += p.x;  acc[5] += p.y;
    p = __builtin_amdgcn_cvt_pk_f32_fp8(v.y, true);  acc[6] += p.x;  acc[7] += p.y;
    p = __builtin_amdgcn_cvt_pk_f32_fp8(v.z, false); acc[8] += p.x;  acc[9] += p.y;
    p = __builtin_amdgcn_cvt_pk_f32_fp8(v.z, true);  acc[10] += p.x; acc[11] += p.y;
    p = __builtin_amdgcn_cvt_pk_f32_fp8(v.w, false); acc[12] += p.x; acc[13] += p.y;
    p = __builtin_amdgcn_cvt_pk_f32_fp8(v.w, true);  acc[14] += p.x; acc[15] += p.y;
  }
  const float sc = invdeg[n];
  float gacc[16];
  {
    const int nloc = wv * 16 + nl;
    unsigned short hh[16];
#pragma unroll
    for (int u = 0; u < 4; u++) {
      float4 o = xr[(size_t)n * 16 + q * 4 + u];
      float v0 = acc[4 * u + 0] * sc + o.x;
      float v1 = acc[4 * u + 1] * sc + o.y;
      float v2 = acc[4 * u + 2] * sc + o.z;
      float v3 = acc[4 * u + 3] * sc + o.w;
      gacc[4 * u + 0] = v0; gacc[4 * u + 1] = v1;
      gacc[4 * u + 2] = v2; gacc[4 * u + 3] = v3;
      hh[4 * u + 0] = f2bf(v0); hh[4 * u + 1] = f2bf(v1);
      hh[4 * u + 2] = f2bf(v2); hh[4 * u + 3] = f2bf(v3);
    }
    *(uint4*)&sh1[nloc * LROW + q * 16] = *(uint4*)&hh[0];
    *(uint4*)&sh1[nloc * LROW + q * 16 + 8] = *(uint4*)&hh[8];
  }
  // reduce across the wave's 16 nodes (lane bits 2..5) — ALL lanes active, uniform
#pragma unroll
  for (int m = 4; m <= 32; m <<= 1)
#pragma unroll
    for (int k = 0; k < 16; k++) gacc[k] += __shfl_xor(gacc[k], m, 64);
  if (nl == 0) {
#pragma unroll
    for (int k = 0; k < 16; k++) sg[wv][q][k] = gacc[k];
  }
  __syncthreads();
  if (t < 64) {
    int qq = t >> 4, k = t & 15;
    float tot = sg[0][qq][k] + sg[1][qq][k] + sg[2][qq][k] + sg[3][qq][k];
    pm[((size_t)(blockIdx.x >> 5) * 32 + (blockIdx.x & 31)) * 64 + t] = tot;
  }
  {
    // phase B: y2 = fp8(h1 @ W2l.T), A from this wave's own LDS rows
    const int col = lane & 15;
    const int quad = lane >> 4;
    f32x4v a2[4];
#pragma unroll
    for (int ct = 0; ct < 4; ct++) a2[ct] = (f32x4v){0.f, 0.f, 0.f, 0.f};
#pragma unroll
    for (int s = 0; s < 2; s++) {
      bf16x8 a = *(const bf16x8*)&sh1[(wv * 16 + col) * LROW + s * 32 + quad * 8];
#pragma unroll
      for (int ct = 0; ct < 4; ct++) {
        bf16x8 b = *(const bf16x8*)&wb2[(size_t)((s * 4 + ct) * 64 + lane) * 8];
        a2[ct] = __builtin_amdgcn_mfma_f32_16x16x32_bf16(a, b, a2[ct], 0, 0, 0);
      }
    }
#pragma unroll
    for (int ct = 0; ct < 4; ct++) {
#pragma unroll
      for (int reg = 0; reg < 4; reg++) {
        int node = nb + wv * 16 + quad * 4 + reg;
        unsigned pk = (unsigned)__builtin_amdgcn_cvt_pk_fp8_f32(a2[ct][reg],
                                                                a2[ct][reg], 0, false);
        y2[(size_t)node * 64 + ct * 16 + col] = (unsigned char)(pk & 0xff);
      }
    }
  }
}

// ---- LEAN partials-only gather (round-11 recovery): the round-8 template
// instantiation carried the fused path's dead 9KB sh1 LDS + VGPR bloat,
// costing ~7us of occupancy (43.8 -> 51.4us). Standalone kernel: LDS = 1KB.
__global__ __launch_bounds__(256) void gatherp_k(const uint4* __restrict__ yb,
                                                 const int* __restrict__ csr,
                                                 const int* __restrict__ rowPtr,
                                                 const float* __restrict__ invdeg,
                                                 float* __restrict__ pm) {
  __shared__ float sg[4][4][16];
  const int t = threadIdx.x;
  const int lane = t & 63;
  const int wv = t >> 6;
  const int q = lane & 3;
  const int nl = lane >> 2;
  const int nb = blockIdx.x * 64;
  const int n = nb + wv * 16 + nl;
  const int rp0 = rowPtr[n], rp1 = rowPtr[n + 1];
  float acc[16];
#pragma unroll
  for (int k = 0; k < 16; k++) acc[k] = 0.f;
  for (int e = rp0; e < rp1; e++) {
    int s = csr[e];
    uint4 v = yb[(size_t)s * 4 + q];
    f32x2 p;
    p = __builtin_amdgcn_cvt_pk_f32_fp8(v.x, false); acc[0] += p.x;  acc[1] += p.y;
    p = __builtin_amdgcn_cvt_pk_f32_fp8(v.x, true);  acc[2] += p.x;  acc[3] += p.y;
    p = __builtin_amdgcn_cvt_pk_f32_fp8(v.y, false); acc[4] += p.x;  acc[5] += p.y;
    p = __builtin_amdgcn_cvt_pk_f32_fp8(v.y, true);  acc[6] += p.x;  acc[7] += p.y;
    p = __builtin_amdgcn_cvt_pk_f32_fp8(v.z, false); acc[8] += p.x;  acc[9] += p.y;
    p = __builtin_amdgcn_cvt_pk_f32_fp8(v.z, true);  acc[10] += p.x; acc[11] += p.y;
    p = __builtin_amdgcn_cvt_pk_f32_fp8(v.w, false); acc[12] += p.x; acc[13] += p.y;
    p = __builtin_amdgcn_cvt_pk_f32_fp8(v.w, true);  acc[14] += p.x; acc[15] += p.y;
  }
  const float sc = invdeg[n];
  float gacc[16];
#pragma unroll
  for (int k = 0; k < 16; k++) gacc[k] = acc[k] * sc;
#pragma unroll
  for (int m = 4; m <= 32; m <<= 1)
#pragma unroll
    for (int k = 0; k < 16; k++) gacc[k] += __shfl_xor(gacc[k], m, 64);
  if (nl == 0) {
#pragma unroll
    for (int k = 0; k < 16; k++) sg[wv][q][k] = gacc[k];
  }
  __syncthreads();
  if (t < 64) {
    int qq = t >> 4, k = t & 15;
    float tot = sg[0][qq][k] + sg[1][qq][k] + sg[2][qq][k] + sg[3][qq][k];
    pm[((size_t)(blockIdx.x >> 5) * 32 + (blockIdx.x & 31)) * 64 + t] = tot;
  }
}

// ---- deterministic partial reduce: gm[b][j] = (1/2048) * sum_blk pm[b][blk][j] ----
__global__ __launch_bounds__(256) void reduce_part_k(const float* __restrict__ pm,
                                                     float* __restrict__ gm) {
  int idx = blockIdx.x * 256 + threadIdx.x;   // 4096
  int b = idx >> 6, j = idx & 63;
  float acc = 0.0f;
  for (int blk = 0; blk < 32; blk++) acc += pm[((size_t)b * 32 + blk) * 64 + j];
  gm[idx] = acc * (1.0f / 2048.0f);
}

// ---- g[b][j] = gmean2[b][j] + b2l[j] + sum_k gmean1[b][k] * W2r[j][k] ----
__global__ __launch_bounds__(256) void combine_k(const float* __restrict__ gmean2,
                                                 const float* __restrict__ gmean1,
                                                 const float* __restrict__ b2l,
                                                 const float* __restrict__ W2r,
                                                 float* __restrict__ g) {
  int idx = blockIdx.x * 256 + threadIdx.x;   // 4096
  int b = idx >> 6, j = idx & 63;
  const float4* m4 = (const float4*)(gmean1 + b * 64);
  const float4* w4 = (const float4*)(W2r + j * 64);
  float acc = gmean2[idx] + b2l[j];
#pragma unroll
  for (int k4 = 0; k4 < 16; k4++) {
    float4 mv = m4[k4], wv = w4[k4];
    acc += mv.x * wv.x + mv.y * wv.y + mv.z * wv.z + mv.w * wv.w;
  }
  g[idx] = acc;
}

// ---- h = relu(g @ fc1_W.T + fc1_b)   g:[64,64] fc1_W:[128,64] -> h:[64,128] ----
__global__ __launch_bounds__(256) void mlp1_k(const float* __restrict__ g,
                                              const float* __restrict__ fc1_W,
                                              const float* __restrict__ fc1_b,
                                              float* __restrict__ h) {
  int idx = blockIdx.x * 256 + threadIdx.x;
  int b = idx >> 7, k = idx & 127;
  const float4* g4 = (const float4*)(g + b * 64);
  const float4* w4 = (const float4*)(fc1_W + k * 64);
  float acc = fc1_b[k];
#pragma unroll
  for (int j4 = 0; j4 < 16; j4++) {
    float4 gv = g4[j4], wv = w4[j4];
    acc += gv.x * wv.x + gv.y * wv.y + gv.z * wv.z + gv.w * wv.w;
  }
  h[idx] = fmaxf(acc, 0.0f);
}

// ---- q = h @ fc2_W.T + fc2_b   h:[64,128] fc2_W:[2048,128] -> q:[64,2048] ----
__global__ __launch_bounds__(256) void mlp2_k(const float* __restrict__ h,
                                              const float* __restrict__ fc2_W,
                                              const float* __restrict__ fc2_b,
                                              float* __restrict__ out) {
  __shared__ float4 sh[32];
  int b = blockIdx.x >> 3;
  int a = (blockIdx.x & 7) * 256 + threadIdx.x;
  if (threadIdx.x < 32) sh[threadIdx.x] = ((const float4*)(h + b * 128))[threadIdx.x];
  __syncthreads();
  const float4* w4 = (const float4*)(fc2_W + (size_t)a * 128);
  float acc = fc2_b[a];
#pragma unroll
  for (int k4 = 0; k4 < 32; k4++) {
    float4 hv = sh[k4], wv = w4[k4];
    acc += hv.x * wv.x + hv.y * wv.y + hv.z * wv.z + hv.w * wv.w;
  }
  out[b * 2048 + a] = acc;
}

extern "C" void kernel_launch(void* const* d_in, const int* in_sizes, int n_in,
                              void* d_out, int out_size, void* d_ws, size_t ws_size,
                              hipStream_t stream) {
  const float* x     = (const float*)d_in[0];
  const int*   ei    = (const int*)d_in[1];
  const float* W1l   = (const float*)d_in[2];
  const float* b1l   = (const float*)d_in[3];
  const float* W1r   = (const float*)d_in[4];
  const float* W2l   = (const float*)d_in[5];
  const float* b2l   = (const float*)d_in[6];
  const float* W2r   = (const float*)d_in[7];
  const float* fc1_W = (const float*)d_in[8];
  const float* fc1_b = (const float*)d_in[9];
  const float* fc2_W = (const float*)d_in[10];
  const float* fc2_b = (const float*)d_in[11];
  float* out = (float*)d_out;

  const int N = in_sizes[0] / D_IN;   // 131072
  const int E = in_sizes[1] / 2;      // 2097152
  const int* src = ei;
  const int* dst = ei + E;

  // workspace layout (~70 MiB; 78 MiB proven available)
  char* ws = (char*)d_ws;
  int*   deg    = (int*)ws;     ws += (size_t)N * 4;
  int*   rowPtr = (int*)ws;     ws += (size_t)(N + 256) * 4;
  int*   bsum   = (int*)ws;     ws += 512 * 4;
  float* invdeg = (float*)ws;   ws += (size_t)N * 4;
  float* gmean1 = (float*)ws;   ws += 4096 * 4;
  float* gmean2 = (float*)ws;   ws += 4096 * 4;
  float* g      = (float*)ws;   ws += 4096 * 4;
  float* hbuf   = (float*)ws;   ws += 8192 * 4;
  unsigned short* wb1l = (unsigned short*)ws;  ws += 8192 * 2;  // mfma-packed bf16
  unsigned short* wb1r = (unsigned short*)ws;  ws += 8192 * 2;
  unsigned short* wb2l = (unsigned short*)ws;  ws += 4096 * 2;
  int*   sh     = (int*)ws;     ws += (size_t)256 * 1024 * 4;  // pass-0 [bin][chunk]
  int*   bh     = (int*)ws;     ws += (size_t)256 * 1024 * 4;  // pass-1 [bin][chunk]
  int*   tot    = (int*)ws;     ws += 256 * 4;
  int*   ssub   = (int*)ws;     ws += 260 * 4;    // src-bucket starts [257]
  int*   sbase  = (int*)ws;     ws += 260 * 4;    // dst-sub starts [257]
  float* p1     = (float*)ws;   ws += (size_t)64 * 32 * 64 * 4;  // graph-mean partials
  float* p2     = (float*)ws;   ws += (size_t)64 * 32 * 64 * 4;
  unsigned int* bkt = (unsigned int*)ws;  ws += (size_t)E * 4;   // sub-binned edges
  int*   csr    = (int*)ws;     ws += (size_t)E * 4;
  unsigned char* bufA = (unsigned char*)ws;  ws += (size_t)64 * N;      // y1 fp8
  unsigned char* bufD = (unsigned char*)ws;  ws += (size_t)64 * N;      // y2 fp8
  float* bufB   = (float*)ws;   ws += (size_t)64 * N * 4;  // xr (fp32)
  size_t used = (size_t)(ws - (char*)d_ws);

  // Aliases (temporally disjoint):
  //   srcS -> bufD (read by bfill1; bufD written later by gatherf)
  //   dstS -> bufA (read by bhist1/bfill1; bufA written later by gemm1)
  int* srcS = (int*)bufD;
  int* dstS = (int*)bufA;

  // Zero the ENTIRE used workspace every call (round-10 fix: every call must
  // start from the identical, validated-benign state; ~11 us at HBM write BW).
  hipMemsetAsync(d_ws, 0, used, stream);

  wprep_mfma_k<<<4, 256, 0, stream>>>(W1l, wb1l, 128);
  wprep_mfma_k<<<4, 256, 0, stream>>>(W1r, wb1r, 128);
  wprep_mfma_k<<<2, 256, 0, stream>>>(W2l, wb2l, 64);

  // CSR build: pass-0 coarse src-sort, pass-1 dst-sub sort (order-preserving
  // at chunk level), then per-sub LDS histogram + counting scatter.
  const int nch = (E + 2047) >> 11;   // 1024 for E=2M (hist rows sized 1024)
  bhist1_k<<<nch, 256, 0, stream>>>(src, sh, E);
  scanA_k<<<256, 256, 0, stream>>>(sh, tot);
  scanB_k<<<1, 256, 0, stream>>>(tot, ssub);
  sfill_k<<<nch, 256, 0, stream>>>(src, dst, sh, ssub, srcS, dstS, E);
  bhist1_k<<<nch, 256, 0, stream>>>(dstS, bh, E);
  scanA_k<<<256, 256, 0, stream>>>(bh, tot);
  scanB_k<<<1, 256, 0, stream>>>(tot, sbase);
  bfill1_k<<<nch, 256, 0, stream>>>(srcS, dstS, bh, sbase, bkt, E);
  deg4_k<<<256, 256, 0, stream>>>(bkt, sbase, deg);
  blocksum_k<<<N / 256, 256, 0, stream>>>(deg, bsum);
  scanbsum_k<<<1, 256, 0, stream>>>(bsum);
  rowptr_k<<<N / 256, 256, 0, stream>>>(deg, bsum, rowPtr, invdeg);
  scat4_k<<<256, 256, 0, stream>>>(bkt, sbase, rowPtr, csr);

  // conv1: y1 = fp8(x@W1l.T) -> bufA ; xr = b1l + x@W1r.T -> bufB (fp32)
  gemm1_k<<<N / 64, 256, 0, stream>>>((const float4*)x, wb1l, wb1r, b1l, bufA, bufB);
  // FUSED: h1 = bf16(gather(y1)*inv + xr) in LDS ; y2 = fp8(h1@W2l.T) -> bufD ;
  // p1 partials (fp32)
  gatherf_k<<<N / 64, 256, 0, stream>>>((const uint4*)bufA, csr, rowPtr, invdeg,
                                        (const float4*)bufB, wb2l, bufD, p1);
  reduce_part_k<<<16, 256, 0, stream>>>(p1, gmean1);

  // conv2 aggregation: lean dst-major gather over y2 (proven 43.8us shape)
  gatherp_k<<<N / 64, 256, 0, stream>>>((const uint4*)bufD, csr, rowPtr, invdeg, p2);
  reduce_part_k<<<16, 256, 0, stream>>>(p2, gmean2);

  // g = gmean2 + b2l + gmean1 @ W2r.T
  combine_k<<<16, 256, 0, stream>>>(gmean2, gmean1, b2l, W2r, g);
  mlp1_k<<<32, 256, 0, stream>>>(g, fc1_W, fc1_b, hbuf);
  mlp2_k<<<512, 256, 0, stream>>>(hbuf, fc2_W, fc2_b, out);
}

// Round 12
// 346.148 us; speedup vs baseline: 3.0011x; 1.0187x over previous
//
#include <hip/hip_runtime.h>
#include <hip/hip_bf16.h>

#define D_IN 128
#define D_EMB 64

typedef float f32x2 __attribute__((ext_vector_type(2)));
typedef float f32x4v __attribute__((ext_vector_type(4)));
typedef short bf16x8 __attribute__((ext_vector_type(8)));   // 8 bf16 = 4 VGPRs (guide §3)

static __device__ __forceinline__ unsigned short f2bf(float f) {
  __hip_bfloat16 h = __float2bfloat16(f);
  return *(unsigned short*)&h;
}
static __device__ __forceinline__ float bf2f(unsigned short u) {
  return __uint_as_float((unsigned)u << 16);
}

// ---- MFMA weight prep: W[64][K] fp32 -> packed bf16 B-fragments.
// frag index tid=(s*4+ct)*64+lane holds W[ct*16+(lane&15)][s*32+(lane>>4)*8 + j], j=0..7
__global__ __launch_bounds__(256) void wprep_mfma_k(const float* __restrict__ W,
                                                    unsigned short* __restrict__ out,
                                                    int K) {
  int tid = blockIdx.x * 256 + threadIdx.x;
  int total = (K / 32) * 4 * 64;
  if (tid >= total) return;
  int lane = tid & 63;
  int ct = (tid >> 6) & 3;
  int s = tid >> 8;
  int row = ct * 16 + (lane & 15);
  int kk = s * 32 + (lane >> 4) * 8;
  unsigned short tmp[8];
#pragma unroll
  for (int j = 0; j < 8; j++) tmp[j] = f2bf(W[row * K + kk + j]);
  *(uint4*)&out[(size_t)tid * 8] = *(uint4*)tmp;
}

// ==== CSR build (round-17 design, proven): src-sort pass 0 + dst-sub sort ====

// Per-chunk 256-bin histogram of key>>9, written TRANSPOSED h[bin*1024+chunk].
__global__ __launch_bounds__(256) void bhist1_k(const int* __restrict__ key,
                                                int* __restrict__ bh, int E) {
  __shared__ int h[256];
  const int t = threadIdx.x;
  h[t] = 0;
  __syncthreads();
  const int base = blockIdx.x * 2048;
#pragma unroll
  for (int j = 0; j < 8; j++) {
    int e = base + j * 256 + t;
    if (e < E) atomicAdd(&h[key[e] >> 9], 1);
  }
  __syncthreads();
  bh[t * 1024 + blockIdx.x] = h[t];
}

// Per-bin exclusive scan over the 1024 chunks (one block per bin), in place.
__global__ __launch_bounds__(256) void scanA_k(int* __restrict__ bh,
                                               int* __restrict__ bintot) {
  __shared__ int sa[256], sb[256];
  const int t = threadIdx.x;
  int* row = bh + (size_t)blockIdx.x * 1024;
  int v0 = row[t * 4], v1 = row[t * 4 + 1], v2 = row[t * 4 + 2], v3 = row[t * 4 + 3];
  int sum = v0 + v1 + v2 + v3;
  sa[t] = sum;
  __syncthreads();
  int* in = sa;
  int* out = sb;
  for (int st = 1; st < 256; st <<= 1) {
    out[t] = in[t] + (t >= st ? in[t - st] : 0);
    __syncthreads();
    int* tmp = in; in = out; out = tmp;
  }
  int excl = in[t] - sum;
  row[t * 4] = excl;
  row[t * 4 + 1] = excl + v0;
  row[t * 4 + 2] = excl + v0 + v1;
  row[t * 4 + 3] = excl + v0 + v1 + v2;
  if (t == 255) bintot[blockIdx.x] = in[255];
}

// Exclusive scan of the 256 bin totals -> base[256] bucket starts, base[256]=E.
__global__ __launch_bounds__(256) void scanB_k(const int* __restrict__ bintot,
                                               int* __restrict__ base) {
  __shared__ int sa[256], sb[256];
  const int t = threadIdx.x;
  int v = bintot[t];
  sa[t] = v;
  __syncthreads();
  int* in = sa;
  int* out = sb;
  for (int st = 1; st < 256; st <<= 1) {
    out[t] = in[t] + (t >= st ? in[t - st] : 0);
    __syncthreads();
    int* tmp = in; in = out; out = tmp;
  }
  base[t] = in[t] - v;
  if (t == 255) base[256] = in[255];
}

// Pass-0 fill: LDS chunk counting-sort by src>>9, emits parallel (srcS, dstS).
__global__ __launch_bounds__(256) void sfill_k(const int* __restrict__ src,
                                               const int* __restrict__ dst,
                                               const int* __restrict__ sh,
                                               const int* __restrict__ ssub,
                                               int* __restrict__ srcS,
                                               int* __restrict__ dstS, int E) {
  __shared__ int hA[256], hB[256], runCur[256], gb[256];
  __shared__ int scache[2048];
  __shared__ int dcache[2048];
  __shared__ int sortS[2048];
  __shared__ int sortD[2048];
  __shared__ unsigned short subb[2048];
  const int t = threadIdx.x;
  const int base = blockIdx.x * 2048;
  const int n = min(2048, E - base);
  hA[t] = 0;
  __syncthreads();
#pragma unroll
  for (int j = 0; j < 8; j++) {
    int idx = j * 256 + t;
    int e = base + idx;
    if (idx < n) {
      int s = src[e];
      scache[idx] = s;
      dcache[idx] = dst[e];
      atomicAdd(&hA[s >> 9], 1);
    }
  }
  __syncthreads();
  int cnt = hA[t];
  int* in = hA;
  int* out = hB;
  for (int st = 1; st < 256; st <<= 1) {
    out[t] = in[t] + (t >= st ? in[t - st] : 0);
    __syncthreads();
    int* tmp = in; in = out; out = tmp;
  }
  int rs = in[t] - cnt;
  __syncthreads();
  hB[t] = rs;
  runCur[t] = rs;
  gb[t] = ssub[t] + sh[t * 1024 + blockIdx.x];
  __syncthreads();
#pragma unroll
  for (int j = 0; j < 8; j++) {
    int idx = j * 256 + t;
    if (idx < n) {
      int s = scache[idx];
      int b = s >> 9;
      int lpos = atomicAdd(&runCur[b], 1);
      sortS[lpos] = s;
      sortD[lpos] = dcache[idx];
      subb[lpos] = (unsigned short)b;
    }
  }
  __syncthreads();
  for (int idx = t; idx < n; idx += 256) {
    int b = subb[idx];
    int g = gb[b] + idx - hB[b];
    srcS[g] = sortS[idx];
    dstS[g] = sortD[idx];
  }
}

// Pass-1 fill: LDS chunk counting-sort by dst>>9 reading the src-sorted
// arrays (stable at chunk level -> dst-sub entries stay src-ordered).
// Packed word: (dst&511)<<17 | src  (9b node-in-sub + 17b src, N=2^17).
__global__ __launch_bounds__(256) void bfill1_k(const int* __restrict__ src,
                                                const int* __restrict__ dst,
                                                const int* __restrict__ bh,
                                                const int* __restrict__ sbase,
                                                unsigned int* __restrict__ bkt,
                                                int E) {
  __shared__ int hA[256], hB[256], runCur[256], gb[256];
  __shared__ int dcache[2048];
  __shared__ unsigned int sorted[2048];
  __shared__ unsigned short subb[2048];
  const int t = threadIdx.x;
  const int base = blockIdx.x * 2048;
  const int n = min(2048, E - base);
  hA[t] = 0;
  __syncthreads();
#pragma unroll
  for (int j = 0; j < 8; j++) {
    int idx = j * 256 + t;
    int e = base + idx;
    if (idx < n) {
      int d = dst[e];
      dcache[idx] = d;
      atomicAdd(&hA[d >> 9], 1);
    }
  }
  __syncthreads();
  int cnt = hA[t];
  int* in = hA;
  int* out = hB;
  for (int st = 1; st < 256; st <<= 1) {
    out[t] = in[t] + (t >= st ? in[t - st] : 0);
    __syncthreads();
    int* tmp = in; in = out; out = tmp;
  }
  int rs = in[t] - cnt;
  __syncthreads();
  hB[t] = rs;
  runCur[t] = rs;
  gb[t] = sbase[t] + bh[t * 1024 + blockIdx.x];
  __syncthreads();
#pragma unroll
  for (int j = 0; j < 8; j++) {
    int idx = j * 256 + t;
    int e = base + idx;
    if (idx < n) {
      int d = dcache[idx];
      int b = d >> 9;
      int lpos = atomicAdd(&runCur[b], 1);
      sorted[lpos] = ((unsigned)(d & 511) << 17) | (unsigned)src[e];
      subb[lpos] = (unsigned short)b;
    }
  }
  __syncthreads();
  for (int idx = t; idx < n; idx += 256) {
    int b = subb[idx];
    bkt[gb[b] + idx - hB[b]] = sorted[idx];
  }
}

// Per-sub degree count (own contiguous sub-bucket, 32 iters, atomic-free write).
__global__ __launch_bounds__(256) void deg4_k(const unsigned int* __restrict__ bkt,
                                              const int* __restrict__ sbase,
                                              int* __restrict__ deg) {
  __shared__ int h[512];
  const int t = threadIdx.x;
  h[t] = 0;
  h[t + 256] = 0;
  __syncthreads();
  const int i = blockIdx.x;
  const int lo = sbase[i], hi = sbase[i + 1];
  for (int e = lo + t; e < hi; e += 256) atomicAdd(&h[bkt[e] >> 17], 1);
  __syncthreads();
  deg[i * 512 + t] = h[t];
  deg[i * 512 + t + 256] = h[t + 256];
}

__global__ __launch_bounds__(256) void blocksum_k(const int* __restrict__ deg,
                                                  int* __restrict__ bsum) {
  __shared__ int sm[256];
  int t = threadIdx.x;
  sm[t] = deg[blockIdx.x * 256 + t];
  __syncthreads();
  for (int s = 128; s > 0; s >>= 1) {
    if (t < s) sm[t] += sm[t + s];
    __syncthreads();
  }
  if (t == 0) bsum[blockIdx.x] = sm[0];
}

// single block: exclusive scan of 512 block sums (in place)
__global__ __launch_bounds__(256) void scanbsum_k(int* __restrict__ bsum) {
  __shared__ int a[512], b[512];
  int t = threadIdx.x;
  a[t] = bsum[t];
  a[t + 256] = bsum[t + 256];
  __syncthreads();
  int* in = a;
  int* out = b;
  for (int st = 1; st < 512; st <<= 1) {
    for (int i = t; i < 512; i += 256) out[i] = in[i] + (i >= st ? in[i - st] : 0);
    __syncthreads();
    int* tmp = in; in = out; out = tmp;
  }
  for (int i = t; i < 512; i += 256) bsum[i] = (i == 0) ? 0 : in[i - 1];
}

// per-block inclusive scan of deg + block offset -> rowPtr (exclusive), fused invdeg
__global__ __launch_bounds__(256) void rowptr_k(const int* __restrict__ deg,
                                                const int* __restrict__ bsumEx,
                                                int* __restrict__ rowPtr,
                                                float* __restrict__ invdeg) {
  __shared__ int a[256], b[256];
  int t = threadIdx.x;
  int i = blockIdx.x * 256 + t;
  int d = deg[i];
  a[t] = d;
  __syncthreads();
  int* in = a;
  int* out = b;
  for (int st = 1; st < 256; st <<= 1) {
    out[t] = in[t] + (t >= st ? in[t - st] : 0);
    __syncthreads();
    int* tmp = in; in = out; out = tmp;
  }
  int incl = in[t] + bsumEx[blockIdx.x];
  rowPtr[i + 1] = incl;
  invdeg[i] = 1.0f / fmaxf((float)d, 1.0f);
  if (i == 0) rowPtr[0] = 0;
}

// Per-sub LDS counting scatter; sequential read preserves src-sorted order.
#define CSR_CAP 12032
__global__ __launch_bounds__(256) void scat4_k(const unsigned int* __restrict__ bkt,
                                               const int* __restrict__ sbase,
                                               const int* __restrict__ rowPtr,
                                               int* __restrict__ csr) {
  __shared__ int cur[512];
  __shared__ int cbuf[CSR_CAP];
  const int t = threadIdx.x;
  const int i = blockIdx.x;
  const int node0 = i * 512;
  const int base0 = rowPtr[node0];
  cur[t] = rowPtr[node0 + t] - base0;
  cur[t + 256] = rowPtr[node0 + t + 256] - base0;
  __syncthreads();
  const int lo = sbase[i], hi = sbase[i + 1];
  for (int e = lo + t; e < hi; e += 256) {
    unsigned v = bkt[e];
    int pos = atomicAdd(&cur[v >> 17], 1);
    int sval = (int)(v & 0x1FFFFu);
    if (pos < CSR_CAP) cbuf[pos] = sval;
    else csr[base0 + pos] = sval;   // never taken for uniform-random input
  }
  __syncthreads();
  const int cnt = rowPtr[node0 + 512] - base0;
  const int lim = cnt < CSR_CAP ? cnt : CSR_CAP;
  for (int idx = t; idx < lim; idx += 256) csr[base0 + idx] = cbuf[idx];
}

// ---- round-12: block-local degree-rank permutation. Sorting the 64 nodes of
// each gather block by degree gives each wave 16 similar-degree nodes ->
// ~21% fewer wave-max iterations (E[max16 Poisson(16)]=23 vs sorted ~18).
// Permutation is WITHIN the 64-node block: all access windows (rowPtr,
// invdeg, csr, xr, y2 rows, graph/pm mapping) unchanged -> zero added scatter.
__global__ __launch_bounds__(256) void nperm_k(const int* __restrict__ deg,
                                               int* __restrict__ perm) {
  __shared__ int dg[256];
  const int t = threadIdx.x;
  const int n0 = blockIdx.x * 256;
  int myd = deg[n0 + t];
  dg[t] = myd;
  __syncthreads();
  const int g0 = t & ~63;   // local 64-group base
  int rank = 0;
#pragma unroll
  for (int j = 0; j < 64; j++) {
    int dj = dg[g0 + j];
    rank += (dj < myd) || (dj == myd && (g0 + j) < t);
  }
  perm[n0 + g0 + rank] = n0 + t;
}

// ---- conv1 MFMA GEMM (LDS-free, round-18 structure).
// out1 = fp8_e4m3(x @ W1l.T) ; out2 = bf16(b1l + x @ W1r.T)  [round-12: bf16
// xr halves the 32MB fp32 round-trip; h1 is rounded to bf16 right after the
// add anyway, so the change is <=1 bf16 ulp on h1]
__global__ __launch_bounds__(256) void gemm1_k(const float4* __restrict__ x4,
                                               const unsigned short* __restrict__ wb1,
                                               const unsigned short* __restrict__ wb2,
                                               const float* __restrict__ bias2,
                                               unsigned char* __restrict__ out1,
                                               unsigned short* __restrict__ out2) {
  constexpr int K = 128, K4 = K / 4;
  const int t = threadIdx.x;
  const int lane = t & 63;
  const int wv = t >> 6;
  const int col = lane & 15;
  const int quad = lane >> 4;
  const int nb = blockIdx.x * 64;
  const int arow = nb + wv * 16 + col;   // A-fragment row (m = lane&15)
  f32x4v acc1[4], acc2[4];
#pragma unroll
  for (int ct = 0; ct < 4; ct++) {
    acc1[ct] = (f32x4v){0.f, 0.f, 0.f, 0.f};
    float bj = bias2[ct * 16 + col];
    acc2[ct] = (f32x4v){bj, bj, bj, bj};
  }
#pragma unroll
  for (int s = 0; s < K / 32; s++) {
    float4 f0 = x4[(size_t)arow * K4 + s * 8 + quad * 2];
    float4 f1 = x4[(size_t)arow * K4 + s * 8 + quad * 2 + 1];
    unsigned short h[8];
    h[0] = f2bf(f0.x); h[1] = f2bf(f0.y); h[2] = f2bf(f0.z); h[3] = f2bf(f0.w);
    h[4] = f2bf(f1.x); h[5] = f2bf(f1.y); h[6] = f2bf(f1.z); h[7] = f2bf(f1.w);
    bf16x8 a = *(const bf16x8*)h;
#pragma unroll
    for (int ct = 0; ct < 4; ct++) {
      bf16x8 b1 = *(const bf16x8*)&wb1[(size_t)((s * 4 + ct) * 64 + lane) * 8];
      acc1[ct] = __builtin_amdgcn_mfma_f32_16x16x32_bf16(a, b1, acc1[ct], 0, 0, 0);
      bf16x8 b2 = *(const bf16x8*)&wb2[(size_t)((s * 4 + ct) * 64 + lane) * 8];
      acc2[ct] = __builtin_amdgcn_mfma_f32_16x16x32_bf16(a, b2, acc2[ct], 0, 0, 0);
    }
  }
#pragma unroll
  for (int ct = 0; ct < 4; ct++) {
#pragma unroll
    for (int reg = 0; reg < 4; reg++) {
      int node = nb + wv * 16 + quad * 4 + reg;
      unsigned pk = (unsigned)__builtin_amdgcn_cvt_pk_fp8_f32(acc1[ct][reg],
                                                              acc1[ct][reg], 0, false);
      out1[(size_t)node * 64 + ct * 16 + col] = (unsigned char)(pk & 0xff);
      out2[(size_t)node * 64 + ct * 16 + col] = f2bf(acc2[ct][reg]);
    }
  }
}

// ---- fused gather + conv2 GEMM (round-19 structure + round-12 perm) ----
// h1 = bf16(gather(y1)*inv + xr) in wave-local LDS; y2 = fp8(h1@W2l.T); p1
// graph-mean partials. Nodes processed in block-local degree-rank order.
#define LROW 72
__global__ __launch_bounds__(256) void gatherf_k(const uint4* __restrict__ yb,
                                                 const int* __restrict__ csr,
                                                 const int* __restrict__ rowPtr,
                                                 const float* __restrict__ invdeg,
                                                 const unsigned short* __restrict__ xr,
                                                 const int* __restrict__ perm,
                                                 const unsigned short* __restrict__ wb2,
                                                 unsigned char* __restrict__ y2,
                                                 float* __restrict__ pm) {
  __shared__ float sg[4][4][16];
  __shared__ unsigned short sh1[64 * LROW];
  __shared__ int sp[64];
  const int t = threadIdx.x;
  if (t < 64) sp[t] = perm[blockIdx.x * 64 + t];
  __syncthreads();
  const int lane = t & 63;
  const int wv = t >> 6;
  const int q = lane & 3;     // 16-B quarter of the 64-B row
  const int nl = lane >> 2;   // node within wave (0..15)
  const int n = sp[wv * 16 + nl];
  const int rp0 = rowPtr[n], rp1 = rowPtr[n + 1];
  float acc[16];
#pragma unroll
  for (int k = 0; k < 16; k++) acc[k] = 0.f;
  for (int e = rp0; e < rp1; e++) {
    int s = csr[e];
    uint4 v = yb[(size_t)s * 4 + q];
    f32x2 p;
    p = __builtin_amdgcn_cvt_pk_f32_fp8(v.x, false); acc[0] += p.x;  acc[1] += p.y;
    p = __builtin_amdgcn_cvt_pk_f32_fp8(v.x, true);  acc[2] += p.x;  acc[3] += p.y;
    p = __builtin_amdgcn_cvt_pk_f32_fp8(v.y, false); acc[4] += p.x;  acc[5] += p.y;
    p = __builtin_amdgcn_cvt_pk_f32_fp8(v.y, true);  acc[6] += p.x;  acc[7] += p.y;
    p = __builtin_amdgcn_cvt_pk_f32_fp8(v.z, false); acc[8] += p.x;  acc[9] += p.y;
    p = __builtin_amdgcn_cvt_pk_f32_fp8(v.z, true);  acc[10] += p.x; acc[11] += p.y;
    p = __builtin_amdgcn_cvt_pk_f32_fp8(v.w, false); acc[12] += p.x; acc[13] += p.y;
    p = __builtin_amdgcn_cvt_pk_f32_fp8(v.w, true);  acc[14] += p.x; acc[15] += p.y;
  }
  const float sc = invdeg[n];
  float gacc[16];
  {
    const int nloc = wv * 16 + nl;
    unsigned short hh[16];
#pragma unroll
    for (int u = 0; u < 4; u++) {
      ushort4 ob = *(const ushort4*)&xr[(size_t)n * 64 + q * 16 + u * 4];
      float v0 = acc[4 * u + 0] * sc + bf2f(ob.x);
      float v1 = acc[4 * u + 1] * sc + bf2f(ob.y);
      float v2 = acc[4 * u + 2] * sc + bf2f(ob.z);
      float v3 = acc[4 * u + 3] * sc + bf2f(ob.w);
      gacc[4 * u + 0] = v0; gacc[4 * u + 1] = v1;
      gacc[4 * u + 2] = v2; gacc[4 * u + 3] = v3;
      hh[4 * u + 0] = f2bf(v0); hh[4 * u + 1] = f2bf(v1);
      hh[4 * u + 2] = f2bf(v2); hh[4 * u + 3] = f2bf(v3);
    }
    *(uint4*)&sh1[nloc * LROW + q * 16] = *(uint4*)&hh[0];
    *(uint4*)&sh1[nloc * LROW + q * 16 + 8] = *(uint4*)&hh[8];
  }
  // reduce across the wave's 16 nodes (lane bits 2..5) — ALL lanes active, uniform
#pragma unroll
  for (int m = 4; m <= 32; m <<= 1)
#pragma unroll
    for (int k = 0; k < 16; k++) gacc[k] += __shfl_xor(gacc[k], m, 64);
  if (nl == 0) {
#pragma unroll
    for (int k = 0; k < 16; k++) sg[wv][q][k] = gacc[k];
  }
  __syncthreads();
  if (t < 64) {
    int qq = t >> 4, k = t & 15;
    float tot = sg[0][qq][k] + sg[1][qq][k] + sg[2][qq][k] + sg[3][qq][k];
    pm[((size_t)(blockIdx.x >> 5) * 32 + (blockIdx.x & 31)) * 64 + t] = tot;
  }
  {
    // phase B: y2 = fp8(h1 @ W2l.T), A from this wave's own LDS rows;
    // output row m maps to global node sp[wv*16+m].
    const int col = lane & 15;
    const int quad = lane >> 4;
    f32x4v a2[4];
#pragma unroll
    for (int ct = 0; ct < 4; ct++) a2[ct] = (f32x4v){0.f, 0.f, 0.f, 0.f};
#pragma unroll
    for (int s = 0; s < 2; s++) {
      bf16x8 a = *(const bf16x8*)&sh1[(wv * 16 + col) * LROW + s * 32 + quad * 8];
#pragma unroll
      for (int ct = 0; ct < 4; ct++) {
        bf16x8 b = *(const bf16x8*)&wb2[(size_t)((s * 4 + ct) * 64 + lane) * 8];
        a2[ct] = __builtin_amdgcn_mfma_f32_16x16x32_bf16(a, b, a2[ct], 0, 0, 0);
      }
    }
#pragma unroll
    for (int ct = 0; ct < 4; ct++) {
#pragma unroll
      for (int reg = 0; reg < 4; reg++) {
        int node = sp[wv * 16 + quad * 4 + reg];
        unsigned pk = (unsigned)__builtin_amdgcn_cvt_pk_fp8_f32(a2[ct][reg],
                                                                a2[ct][reg], 0, false);
        y2[(size_t)node * 64 + ct * 16 + col] = (unsigned char)(pk & 0xff);
      }
    }
  }
}

// ---- LEAN partials-only gather (+ round-12 perm) ----
__global__ __launch_bounds__(256) void gatherp_k(const uint4* __restrict__ yb,
                                                 const int* __restrict__ csr,
                                                 const int* __restrict__ rowPtr,
                                                 const float* __restrict__ invdeg,
                                                 const int* __restrict__ perm,
                                                 float* __restrict__ pm) {
  __shared__ float sg[4][4][16];
  __shared__ int sp[64];
  const int t = threadIdx.x;
  if (t < 64) sp[t] = perm[blockIdx.x * 64 + t];
  __syncthreads();
  const int lane = t & 63;
  const int wv = t >> 6;
  const int q = lane & 3;
  const int nl = lane >> 2;
  const int n = sp[wv * 16 + nl];
  const int rp0 = rowPtr[n], rp1 = rowPtr[n + 1];
  float acc[16];
#pragma unroll
  for (int k = 0; k < 16; k++) acc[k] = 0.f;
  for (int e = rp0; e < rp1; e++) {
    int s = csr[e];
    uint4 v = yb[(size_t)s * 4 + q];
    f32x2 p;
    p = __builtin_amdgcn_cvt_pk_f32_fp8(v.x, false); acc[0] += p.x;  acc[1] += p.y;
    p = __builtin_amdgcn_cvt_pk_f32_fp8(v.x, true);  acc[2] += p.x;  acc[3] += p.y;
    p = __builtin_amdgcn_cvt_pk_f32_fp8(v.y, false); acc[4] += p.x;  acc[5] += p.y;
    p = __builtin_amdgcn_cvt_pk_f32_fp8(v.y, true);  acc[6] += p.x;  acc[7] += p.y;
    p = __builtin_amdgcn_cvt_pk_f32_fp8(v.z, false); acc[8] += p.x;  acc[9] += p.y;
    p = __builtin_amdgcn_cvt_pk_f32_fp8(v.z, true);  acc[10] += p.x; acc[11] += p.y;
    p = __builtin_amdgcn_cvt_pk_f32_fp8(v.w, false); acc[12] += p.x; acc[13] += p.y;
    p = __builtin_amdgcn_cvt_pk_f32_fp8(v.w, true);  acc[14] += p.x; acc[15] += p.y;
  }
  const float sc = invdeg[n];
  float gacc[16];
#pragma unroll
  for (int k = 0; k < 16; k++) gacc[k] = acc[k] * sc;
#pragma unroll
  for (int m = 4; m <= 32; m <<= 1)
#pragma unroll
    for (int k = 0; k < 16; k++) gacc[k] += __shfl_xor(gacc[k], m, 64);
  if (nl == 0) {
#pragma unroll
    for (int k = 0; k < 16; k++) sg[wv][q][k] = gacc[k];
  }
  __syncthreads();
  if (t < 64) {
    int qq = t >> 4, k = t & 15;
    float tot = sg[0][qq][k] + sg[1][qq][k] + sg[2][qq][k] + sg[3][qq][k];
    pm[((size_t)(blockIdx.x >> 5) * 32 + (blockIdx.x & 31)) * 64 + t] = tot;
  }
}

// ---- merged deterministic partial reduce: blocks 0-15 -> p1/gmean1,
// blocks 16-31 -> p2/gmean2 (one dispatch instead of two).
__global__ __launch_bounds__(256) void reduce_both_k(const float* __restrict__ p1,
                                                     const float* __restrict__ p2,
                                                     float* __restrict__ gm1,
                                                     float* __restrict__ gm2) {
  int half = blockIdx.x >> 4;
  int idx = (blockIdx.x & 15) * 256 + threadIdx.x;   // 4096 per half
  const float* pm = half ? p2 : p1;
  float* gm = half ? gm2 : gm1;
  int b = idx >> 6, j = idx & 63;
  float acc = 0.0f;
  for (int blk = 0; blk < 32; blk++) acc += pm[((size_t)b * 32 + blk) * 64 + j];
  gm[idx] = acc * (1.0f / 2048.0f);
}

// ---- g[b][j] = gmean2[b][j] + b2l[j] + sum_k gmean1[b][k] * W2r[j][k] ----
__global__ __launch_bounds__(256) void combine_k(const float* __restrict__ gmean2,
                                                 const float* __restrict__ gmean1,
                                                 const float* __restrict__ b2l,
                                                 const float* __restrict__ W2r,
                                                 float* __restrict__ g) {
  int idx = blockIdx.x * 256 + threadIdx.x;   // 4096
  int b = idx >> 6, j = idx & 63;
  const float4* m4 = (const float4*)(gmean1 + b * 64);
  const float4* w4 = (const float4*)(W2r + j * 64);
  float acc = gmean2[idx] + b2l[j];
#pragma unroll
  for (int k4 = 0; k4 < 16; k4++) {
    float4 mv = m4[k4], wv = w4[k4];
    acc += mv.x * wv.x + mv.y * wv.y + mv.z * wv.z + mv.w * wv.w;
  }
  g[idx] = acc;
}

// ---- h = relu(g @ fc1_W.T + fc1_b)   g:[64,64] fc1_W:[128,64] -> h:[64,128] ----
__global__ __launch_bounds__(256) void mlp1_k(const float* __restrict__ g,
                                              const float* __restrict__ fc1_W,
                                              const float* __restrict__ fc1_b,
                                              float* __restrict__ h) {
  int idx = blockIdx.x * 256 + threadIdx.x;
  int b = idx >> 7, k = idx & 127;
  const float4* g4 = (const float4*)(g + b * 64);
  const float4* w4 = (const float4*)(fc1_W + k * 64);
  float acc = fc1_b[k];
#pragma unroll
  for (int j4 = 0; j4 < 16; j4++) {
    float4 gv = g4[j4], wv = w4[j4];
    acc += gv.x * wv.x + gv.y * wv.y + gv.z * wv.z + gv.w * wv.w;
  }
  h[idx] = fmaxf(acc, 0.0f);
}

// ---- q = h @ fc2_W.T + fc2_b   h:[64,128] fc2_W:[2048,128] -> q:[64,2048] ----
__global__ __launch_bounds__(256) void mlp2_k(const float* __restrict__ h,
                                              const float* __restrict__ fc2_W,
                                              const float* __restrict__ fc2_b,
                                              float* __restrict__ out) {
  __shared__ float4 sh[32];
  int b = blockIdx.x >> 3;
  int a = (blockIdx.x & 7) * 256 + threadIdx.x;
  if (threadIdx.x < 32) sh[threadIdx.x] = ((const float4*)(h + b * 128))[threadIdx.x];
  __syncthreads();
  const float4* w4 = (const float4*)(fc2_W + (size_t)a * 128);
  float acc = fc2_b[a];
#pragma unroll
  for (int k4 = 0; k4 < 32; k4++) {
    float4 hv = sh[k4], wv = w4[k4];
    acc += hv.x * wv.x + hv.y * wv.y + hv.z * wv.z + hv.w * wv.w;
  }
  out[b * 2048 + a] = acc;
}

extern "C" void kernel_launch(void* const* d_in, const int* in_sizes, int n_in,
                              void* d_out, int out_size, void* d_ws, size_t ws_size,
                              hipStream_t stream) {
  const float* x     = (const float*)d_in[0];
  const int*   ei    = (const int*)d_in[1];
  const float* W1l   = (const float*)d_in[2];
  const float* b1l   = (const float*)d_in[3];
  const float* W1r   = (const float*)d_in[4];
  const float* W2l   = (const float*)d_in[5];
  const float* b2l   = (const float*)d_in[6];
  const float* W2r   = (const float*)d_in[7];
  const float* fc1_W = (const float*)d_in[8];
  const float* fc1_b = (const float*)d_in[9];
  const float* fc2_W = (const float*)d_in[10];
  const float* fc2_b = (const float*)d_in[11];
  float* out = (float*)d_out;

  const int N = in_sizes[0] / D_IN;   // 131072
  const int E = in_sizes[1] / 2;      // 2097152
  const int* src = ei;
  const int* dst = ei + E;

  // workspace layout (~55 MiB; 78 MiB proven available)
  char* ws = (char*)d_ws;
  int*   deg    = (int*)ws;     ws += (size_t)N * 4;
  int*   rowPtr = (int*)ws;     ws += (size_t)(N + 256) * 4;
  int*   bsum   = (int*)ws;     ws += 512 * 4;
  float* invdeg = (float*)ws;   ws += (size_t)N * 4;
  int*   perm   = (int*)ws;     ws += (size_t)N * 4;   // degree-rank (block-local)
  float* gmean1 = (float*)ws;   ws += 4096 * 4;
  float* gmean2 = (float*)ws;   ws += 4096 * 4;
  float* g      = (float*)ws;   ws += 4096 * 4;
  float* hbuf   = (float*)ws;   ws += 8192 * 4;
  unsigned short* wb1l = (unsigned short*)ws;  ws += 8192 * 2;  // mfma-packed bf16
  unsigned short* wb1r = (unsigned short*)ws;  ws += 8192 * 2;
  unsigned short* wb2l = (unsigned short*)ws;  ws += 4096 * 2;
  int*   sh     = (int*)ws;     ws += (size_t)256 * 1024 * 4;  // pass-0 [bin][chunk]
  int*   bh     = (int*)ws;     ws += (size_t)256 * 1024 * 4;  // pass-1 [bin][chunk]
  int*   tot    = (int*)ws;     ws += 256 * 4;
  int*   ssub   = (int*)ws;     ws += 260 * 4;    // src-bucket starts [257]
  int*   sbase  = (int*)ws;     ws += 260 * 4;    // dst-sub starts [257]
  float* p1     = (float*)ws;   ws += (size_t)64 * 32 * 64 * 4;  // graph-mean partials
  float* p2     = (float*)ws;   ws += (size_t)64 * 32 * 64 * 4;
  unsigned int* bkt = (unsigned int*)ws;  ws += (size_t)E * 4;   // sub-binned edges
  int*   csr    = (int*)ws;     ws += (size_t)E * 4;
  unsigned char* bufA = (unsigned char*)ws;  ws += (size_t)64 * N;      // y1 fp8
  unsigned char* bufD = (unsigned char*)ws;  ws += (size_t)64 * N;      // y2 fp8
  unsigned short* bufB = (unsigned short*)ws;  ws += (size_t)64 * N * 2;  // xr (bf16)
  size_t used = (size_t)(ws - (char*)d_ws);

  // Aliases (temporally disjoint):
  //   srcS -> bufD (read by bfill1; bufD written later by gatherf)
  //   dstS -> bufA (read by bhist1/bfill1; bufA written later by gemm1)
  int* srcS = (int*)bufD;
  int* dstS = (int*)bufA;

  // Zero the ENTIRE used workspace every call (round-10 fix: every call must
  // start from the identical, validated-benign state; ~9 us at HBM write BW).
  hipMemsetAsync(d_ws, 0, used, stream);

  wprep_mfma_k<<<4, 256, 0, stream>>>(W1l, wb1l, 128);
  wprep_mfma_k<<<4, 256, 0, stream>>>(W1r, wb1r, 128);
  wprep_mfma_k<<<2, 256, 0, stream>>>(W2l, wb2l, 64);

  // CSR build: pass-0 coarse src-sort, pass-1 dst-sub sort (order-preserving
  // at chunk level), then per-sub LDS histogram + counting scatter.
  const int nch = (E + 2047) >> 11;   // 1024 for E=2M (hist rows sized 1024)
  bhist1_k<<<nch, 256, 0, stream>>>(src, sh, E);
  scanA_k<<<256, 256, 0, stream>>>(sh, tot);
  scanB_k<<<1, 256, 0, stream>>>(tot, ssub);
  sfill_k<<<nch, 256, 0, stream>>>(src, dst, sh, ssub, srcS, dstS, E);
  bhist1_k<<<nch, 256, 0, stream>>>(dstS, bh, E);
  scanA_k<<<256, 256, 0, stream>>>(bh, tot);
  scanB_k<<<1, 256, 0, stream>>>(tot, sbase);
  bfill1_k<<<nch, 256, 0, stream>>>(srcS, dstS, bh, sbase, bkt, E);
  deg4_k<<<256, 256, 0, stream>>>(bkt, sbase, deg);
  blocksum_k<<<N / 256, 256, 0, stream>>>(deg, bsum);
  scanbsum_k<<<1, 256, 0, stream>>>(bsum);
  rowptr_k<<<N / 256, 256, 0, stream>>>(deg, bsum, rowPtr, invdeg);
  scat4_k<<<256, 256, 0, stream>>>(bkt, sbase, rowPtr, csr);
  nperm_k<<<N / 256, 256, 0, stream>>>(deg, perm);

  // conv1: y1 = fp8(x@W1l.T) -> bufA ; xr = bf16(b1l + x@W1r.T) -> bufB
  gemm1_k<<<N / 64, 256, 0, stream>>>((const float4*)x, wb1l, wb1r, b1l, bufA, bufB);
  // FUSED: h1 = bf16(gather(y1)*inv + xr) in LDS ; y2 = fp8(h1@W2l.T) -> bufD ;
  // p1 partials (fp32); nodes in degree-rank order
  gatherf_k<<<N / 64, 256, 0, stream>>>((const uint4*)bufA, csr, rowPtr, invdeg,
                                        bufB, perm, wb2l, bufD, p1);
  // conv2 aggregation: lean dst-major gather over y2
  gatherp_k<<<N / 64, 256, 0, stream>>>((const uint4*)bufD, csr, rowPtr, invdeg,
                                        perm, p2);
  reduce_both_k<<<32, 256, 0, stream>>>(p1, p2, gmean1, gmean2);

  // g = gmean2 + b2l + gmean1 @ W2r.T
  combine_k<<<16, 256, 0, stream>>>(gmean2, gmean1, b2l, W2r, g);
  mlp1_k<<<32, 256, 0, stream>>>(g, fc1_W, fc1_b, hbuf);
  mlp2_k<<<512, 256, 0, stream>>>(hbuf, fc2_W, fc2_b, out);
}